// Round 7
// baseline (622.784 us; speedup 1.0000x reference)
//
#include <hip/hip_runtime.h>

// ---------------------------------------------------------------------------
// NodeModel (GraphNet node block), MI355X / gfx950.
// v11: gemm1/gemm2 process 512 rows/block. gemm1 issues BOTH chunks' gathers
//   up-front (2x in-flight loads -> hides L2/L3 gather latency; halves fold
//   executions and per-block stats atomics). gemm2: two sequential 256-row
//   chunks reusing hs; wlds unioned with hs (LDS 51->43KB).
// v10: NBIN=64 hot-line atomic fix (+146us, validated). fold vectorized (v9).
// Aggregation: h written dest-sorted (ipos), gemm2 fuses LDS segment-sum
// -> s_e; agg[n] = bf16(s_e[n]) @ W3' + deg[n]*b3' (BN affine commutes).
// MFMA layouts (verified): A[m=lane&15][k=(lane>>4)*8+j],
//   B[k=(lane>>4)*8+j][n=lane&15], C/D: col=lane&15, row=(lane>>4)*4+reg.
// ---------------------------------------------------------------------------

typedef unsigned short u16;
typedef __bf16  bf16x8  __attribute__((ext_vector_type(8)));
typedef float   floatx4 __attribute__((ext_vector_type(4)));

#define NBIN 64
#define EA_BLOCKS 1024

__device__ __forceinline__ float bf2f(u16 u) {
  union { float f; unsigned int i; } v; v.i = ((unsigned int)u) << 16; return v.f;
}
__device__ __forceinline__ u16 f2bf(float f) {
  union { float f; unsigned int i; } v; v.f = f;
  unsigned int x = v.i;
  return (u16)((x + 0x7fffu + ((x >> 16) & 1u)) >> 16);  // RNE
}
__device__ __forceinline__ bf16x8 ldb8(const u16* p) {
  return *reinterpret_cast<const bf16x8*>(p);
}
__device__ __forceinline__ floatx4 mfma16(bf16x8 a, bf16x8 b, floatx4 c) {
  return __builtin_amdgcn_mfma_f32_16x16x32_bf16(a, b, c, 0, 0, 0);
}
// mode: 0 = float32, 1 = bf16
__device__ __forceinline__ float loadf(const void* p, long idx, int mode) {
  return mode ? bf2f(((const u16*)p)[idx]) : ((const float*)p)[idx];
}
__device__ __forceinline__ bf16x8 load8(const void* p, long idx, int mode) {
  if (mode) return ldb8((const u16*)p + idx);
  const float* f = (const float*)p + idx;
  bf16x8 r;
#pragma unroll
  for (int j = 0; j < 8; j++) r[j] = (__bf16)f[j];
  return r;
}

// ---------------- per-block BN fold: stats -> scale/offset -> packed W+bias
// wlds: K*OUT u16 LDS, wpack: same size, s_s/s_off: K floats, sbias: OUT.
// v9: staging and repack vectorized to 16B ops (was scalar 2B).
__device__ __forceinline__ void fold_block(
    const float* __restrict__ stats, float inv_rows,
    const void* __restrict__ g, const void* __restrict__ b,
    const void* __restrict__ W, const void* __restrict__ c,
    int K, int OUT, int mode,
    u16* wlds, u16* wpack, float* s_s, float* s_off, float* sbias) {
  const int tid = threadIdx.x;
  const int tot8 = (K * OUT) >> 3;  // always divisible by 8
  for (int i = tid; i < tot8; i += 256) {
    bf16x8 o;
    if (mode) {
      o = ldb8((const u16*)W + (size_t)i * 8);
    } else {
      const float* f = (const float*)W + (size_t)i * 8;
      float4 a = *(const float4*)f;
      float4 d = *(const float4*)(f + 4);
      o[0] = (__bf16)a.x; o[1] = (__bf16)a.y; o[2] = (__bf16)a.z; o[3] = (__bf16)a.w;
      o[4] = (__bf16)d.x; o[5] = (__bf16)d.y; o[6] = (__bf16)d.z; o[7] = (__bf16)d.w;
    }
    *reinterpret_cast<bf16x8*>(wlds + (size_t)i * 8) = o;
  }
  if (tid < K) {
    float sum = 0.f, sq = 0.f;
    for (int p = 0; p < NBIN; p++) {
      sum += stats[p * 2 * K + tid];
      sq  += stats[p * 2 * K + K + tid];
    }
    float m = sum * inv_rows, var = sq * inv_rows - m * m;
    float s = loadf(g, tid, mode) * rsqrtf(var + 1e-5f);
    s_s[tid] = s;
    s_off[tid] = loadf(b, tid, mode) - m * s;
  }
  __syncthreads();
  if (tid < OUT) {
    float acc = loadf(c, tid, mode);
    for (int k = 0; k < K; k++) acc += s_off[k] * bf2f(wlds[k * OUT + tid]);
    sbias[tid] = acc;
  }
  const int H = K >> 5, T = OUT >> 4;
  const int tot8p = T * H * 64;  // (T*H*512)/8
  for (int i8 = tid; i8 < tot8p; i8 += 256) {
    int lane = i8 & 63, th = i8 >> 6;
    int h = th % H, t = th / H;
    int kb = h * 32 + ((lane >> 4) << 3);
    int n = (t << 4) + (lane & 15);
    bf16x8 o;
#pragma unroll
    for (int j = 0; j < 8; j++)
      o[j] = (__bf16)(s_s[kb + j] * bf2f(wlds[(kb + j) * OUT + n]));
    *reinterpret_cast<bf16x8*>(wpack + (size_t)i8 * 8) = o;
  }
  __syncthreads();
}

// ---------------- dtype detection
__global__ void detect_kernel(const u16* __restrict__ x, int* __restrict__ modep) {
  __shared__ int cnt;
  if (threadIdx.x == 0) cnt = 0;
  __syncthreads();
  int weird = 0;
  for (int i = threadIdx.x; i < 1024; i += blockDim.x) {
    unsigned e = (x[i] >> 7) & 0xFFu;
    if (e == 0xFFu || e >= 0x90u || (e != 0u && e < 0x60u)) weird++;
  }
  atomicAdd(&cnt, weird);
  __syncthreads();
  if (threadIdx.x == 0) *modep = (cnt > 128) ? 0 : 1;
}

// ================= counting sort of edges by destination ====================
__global__ void count2_kernel(const int* __restrict__ row, const int* __restrict__ col,
                              int E, int* __restrict__ odeg, int* __restrict__ deg) {
  for (int e = blockIdx.x * blockDim.x + threadIdx.x; e < E;
       e += gridDim.x * blockDim.x) {
    atomicAdd(&odeg[row[e]], 1);
    atomicAdd(&deg[col[e]], 1);
  }
}

__global__ void scan1_kernel(const int* __restrict__ deg, int n,
                             int* __restrict__ excl, int* __restrict__ bsum) {
  __shared__ int tmp[2][1024];
  const int tid = threadIdx.x;
  const int i = blockIdx.x * 1024 + tid;
  int v = (i < n) ? deg[i] : 0;
  tmp[0][tid] = v;
  __syncthreads();
  int src = 0;
  for (int off = 1; off < 1024; off <<= 1) {
    int t = tmp[src][tid];
    if (tid >= off) t += tmp[src][tid - off];
    tmp[1 - src][tid] = t;
    src = 1 - src;
    __syncthreads();
  }
  if (i < n) excl[i] = tmp[src][tid] - v;
  if (tid == 1023) bsum[blockIdx.x] = tmp[src][1023];
}

// parallel exclusive scan of up to 1024 block sums
__global__ void scan2_kernel(int* __restrict__ bsum, int nb,
                             int* __restrict__ offsets, int N, int E) {
  __shared__ int tmp[2][1024];
  const int tid = threadIdx.x;
  int v = (tid < nb) ? bsum[tid] : 0;
  tmp[0][tid] = v;
  __syncthreads();
  int src = 0;
  for (int off = 1; off < 1024; off <<= 1) {
    int t = tmp[src][tid];
    if (tid >= off) t += tmp[src][tid - off];
    tmp[1 - src][tid] = t;
    src = 1 - src;
    __syncthreads();
  }
  if (tid < nb) bsum[tid] = tmp[src][tid] - v;
  if (tid == 0) offsets[N] = E;
}

__global__ void scan3_kernel(int* __restrict__ offsets, const int* __restrict__ bsum,
                             int n, int* __restrict__ cursor) {
  int i = blockIdx.x * 1024 + threadIdx.x;
  if (i < n) {
    int v = offsets[i] + bsum[blockIdx.x];
    offsets[i] = v;
    cursor[i] = v;
  }
}

__global__ void scatter_kernel(const int* __restrict__ col, int E,
                               int* __restrict__ cursor, int* __restrict__ ipos,
                               int* __restrict__ nodeof) {
  for (int e = blockIdx.x * blockDim.x + threadIdx.x; e < E;
       e += gridDim.x * blockDim.x) {
    int d = col[e];
    int pos = atomicAdd(&cursor[d], 1);
    ipos[e] = pos;
    nodeof[pos] = d;
  }
}

// ---------------- merged input stats:
// blocks [0,512): x pass -> unweighted stats (statsB0 c0..31), odeg-weighted
//   (stats0 c0..31), and xb = bf16(x).
// blocks [512,512+EA_BLOCKS): ea streaming pass -> stats0 c32..63, linear eab.
// v10: ea-pass cross-wave LDS reduction -> 64 atomics/block (was 256).
__global__ void stats_in_kernel(const void* __restrict__ x,
                                const int* __restrict__ odeg, int N,
                                const void* __restrict__ ea, int E,
                                float* __restrict__ stats0,
                                float* __restrict__ statsB0,
                                u16* __restrict__ xb, u16* __restrict__ eab,
                                const int* __restrict__ modep) {
  const int mode = *modep;
  if (blockIdx.x < 512) {
    const int c = threadIdx.x & 31, rs = threadIdx.x >> 5;  // 8 rows/iter
    float s = 0.f, q = 0.f, ws = 0.f, wq = 0.f;
    for (long rr = (long)blockIdx.x * 8 + rs; rr < N; rr += 512 * 8) {
      float v = loadf(x, rr * 32 + c, mode);
      float w = (float)odeg[rr];
      xb[rr * 32 + c] = f2bf(v);
      s += v; q += v * v; ws += w * v; wq += w * v * v;
    }
    __shared__ float sm[4][256];
    sm[0][threadIdx.x] = s;  sm[1][threadIdx.x] = q;
    sm[2][threadIdx.x] = ws; sm[3][threadIdx.x] = wq;
    __syncthreads();
    if (threadIdx.x < 32) {
      for (int i = 1; i < 8; i++) {
        s  += sm[0][i * 32 + c]; q  += sm[1][i * 32 + c];
        ws += sm[2][i * 32 + c]; wq += sm[3][i * 32 + c];
      }
      const int bin = blockIdx.x & (NBIN - 1);
      atomicAdd(statsB0 + bin * 192 + c, s);
      atomicAdd(statsB0 + bin * 192 + 96 + c, q);
      atomicAdd(stats0 + bin * 128 + c, ws);
      atomicAdd(stats0 + bin * 128 + 64 + c, wq);
    }
  } else {
    const int bid = blockIdx.x - 512;                        // 0..EA_BLOCKS-1
    const int cg = threadIdx.x & 3, rsub = threadIdx.x >> 2;  // 64 rows/iter
    const int lane = threadIdx.x & 63, wave = threadIdx.x >> 6;
    float s[8], q[8];
#pragma unroll
    for (int j = 0; j < 8; j++) { s[j] = 0.f; q[j] = 0.f; }
    for (long rr = (long)bid * 64 + rsub; rr < E; rr += (long)EA_BLOCKS * 64) {
      float f0[8];
      if (mode) {
        bf16x8 v = ldb8((const u16*)ea + rr * 32 + cg * 8);
#pragma unroll
        for (int j = 0; j < 8; j++) f0[j] = (float)v[j];
      } else {
        const float* p = (const float*)ea + rr * 32 + cg * 8;
        float4 a = *(const float4*)p;
        float4 b = *(const float4*)(p + 4);
        f0[0]=a.x; f0[1]=a.y; f0[2]=a.z; f0[3]=a.w;
        f0[4]=b.x; f0[5]=b.y; f0[6]=b.z; f0[7]=b.w;
      }
      if (eab) {
        bf16x8 o;
#pragma unroll
        for (int j = 0; j < 8; j++) o[j] = (__bf16)f0[j];
        *reinterpret_cast<bf16x8*>(eab + rr * 32 + cg * 8) = o;
      }
#pragma unroll
      for (int j = 0; j < 8; j++) { s[j] += f0[j]; q[j] += f0[j] * f0[j]; }
    }
#pragma unroll
    for (int st = 4; st < 64; st <<= 1) {
#pragma unroll
      for (int j = 0; j < 8; j++) {
        s[j] += __shfl_xor(s[j], st, 64);
        q[j] += __shfl_xor(q[j], st, 64);
      }
    }
    // cross-wave LDS reduction: one atomic set per BLOCK (64 adds), not per wave
    __shared__ float red[4][64];
    if (lane < 4) {
#pragma unroll
      for (int j = 0; j < 8; j++) {
        red[wave][lane * 8 + j] = s[j];
        red[wave][32 + lane * 8 + j] = q[j];
      }
    }
    __syncthreads();
    if (wave == 0 && lane < 4) {
      float* o = stats0 + (blockIdx.x & (NBIN - 1)) * 128;
#pragma unroll
      for (int j = 0; j < 8; j++) {
        float ss = red[0][lane * 8 + j] + red[1][lane * 8 + j] +
                   red[2][lane * 8 + j] + red[3][lane * 8 + j];
        float qq = red[0][32 + lane * 8 + j] + red[1][32 + lane * 8 + j] +
                   red[2][32 + lane * 8 + j] + red[3][32 + lane * 8 + j];
        atomicAdd(o + 32 + lane * 8 + j, ss);
        atomicAdd(o + 96 + lane * 8 + j, qq);
      }
    }
  }
}

// ======== GEMM 1: [xb[row[e]], ea[e]] -> h (dest-sorted), LReLU, stats ======
// v11: 512 rows/block; both chunks' gathers issued up-front (2x MLP).
__global__ __launch_bounds__(256) void gemm1_kernel(
    const u16* __restrict__ xb, const u16* __restrict__ eab,
    const int* __restrict__ erow, const int* __restrict__ ipos,
    const float* __restrict__ stats0, float invE,
    const void* __restrict__ g, const void* __restrict__ b,
    const void* __restrict__ W, const void* __restrict__ c,
    u16* __restrict__ hout, int E,
    float* __restrict__ statsOut, const int* __restrict__ modep) {
  __shared__ u16 wlds[4096], wpack[4096];
  __shared__ float s_s[64], s_off[64], sbias[64];
  __shared__ float sm[512];
  const int mode = *modep;
  fold_block(stats0, invE, g, b, W, c, 64, 64, mode, wlds, wpack, s_s, s_off, sbias);
  const int lane = threadIdx.x & 63, wave = threadIdx.x >> 6;
  const int q = lane >> 4, r = lane & 15;
  const long cb0 = (long)blockIdx.x * 512 + wave * 64;
  const long cb1 = cb0 + 256;
  bf16x8 bfr[4][2];
#pragma unroll
  for (int t = 0; t < 4; t++)
#pragma unroll
    for (int h = 0; h < 2; h++)
      bfr[t][h] = *reinterpret_cast<const bf16x8*>(wpack + ((t * 2 + h) * 64 + lane) * 8);
  float bv[4];
#pragma unroll
  for (int t = 0; t < 4; t++) bv[t] = sbias[t * 16 + r];
  // gather BOTH chunks up-front (16x 16B loads in flight per thread)
  bf16x8 A00[4], A10[4], A01[4], A11[4];
  int P0[4][4], P1[4][4];
#pragma unroll
  for (int r4 = 0; r4 < 4; r4++) {
    long e = cb0 + r4 * 16 + r; if (e > E - 1) e = E - 1;
    int src = erow[e];
    A00[r4] = ldb8(xb + (long)src * 32 + q * 8);
    A10[r4] = ldb8(eab + e * 32 + q * 8);
#pragma unroll
    for (int gi = 0; gi < 4; gi++) {
      long row = cb0 + r4 * 16 + q * 4 + gi;
      P0[r4][gi] = (row < E) ? ipos[row] : -1;
    }
  }
#pragma unroll
  for (int r4 = 0; r4 < 4; r4++) {
    long e = cb1 + r4 * 16 + r; if (e > E - 1) e = E - 1;
    int src = erow[e];
    A01[r4] = ldb8(xb + (long)src * 32 + q * 8);
    A11[r4] = ldb8(eab + e * 32 + q * 8);
#pragma unroll
    for (int gi = 0; gi < 4; gi++) {
      long row = cb1 + r4 * 16 + q * 4 + gi;
      P1[r4][gi] = (row < E) ? ipos[row] : -1;
    }
  }
  float s_[4] = {0, 0, 0, 0}, q_[4] = {0, 0, 0, 0};
  // compute chunk 0
#pragma unroll
  for (int r4 = 0; r4 < 4; r4++) {
    floatx4 acc[4];
#pragma unroll
    for (int t = 0; t < 4; t++) {
      acc[t] = (floatx4){bv[t], bv[t], bv[t], bv[t]};
      acc[t] = mfma16(A00[r4], bfr[t][0], acc[t]);
      acc[t] = mfma16(A10[r4], bfr[t][1], acc[t]);
    }
#pragma unroll
    for (int gi = 0; gi < 4; gi++) {
      long p = P0[r4][gi];
      if (p >= 0) {
#pragma unroll
        for (int t = 0; t < 4; t++) {
          float v = acc[t][gi];
          v = v > 0.f ? v : 0.1f * v;
          u16 st = f2bf(v);
          hout[p * 64 + t * 16 + r] = st;
          float vv = bf2f(st);
          s_[t] += vv; q_[t] += vv * vv;
        }
      }
    }
  }
  // compute chunk 1
#pragma unroll
  for (int r4 = 0; r4 < 4; r4++) {
    floatx4 acc[4];
#pragma unroll
    for (int t = 0; t < 4; t++) {
      acc[t] = (floatx4){bv[t], bv[t], bv[t], bv[t]};
      acc[t] = mfma16(A01[r4], bfr[t][0], acc[t]);
      acc[t] = mfma16(A11[r4], bfr[t][1], acc[t]);
    }
#pragma unroll
    for (int gi = 0; gi < 4; gi++) {
      long p = P1[r4][gi];
      if (p >= 0) {
#pragma unroll
        for (int t = 0; t < 4; t++) {
          float v = acc[t][gi];
          v = v > 0.f ? v : 0.1f * v;
          u16 st = f2bf(v);
          hout[p * 64 + t * 16 + r] = st;
          float vv = bf2f(st);
          s_[t] += vv; q_[t] += vv * vv;
        }
      }
    }
  }
#pragma unroll
  for (int t = 0; t < 4; t++) {
    float s = s_[t], qq = q_[t];
    s  += __shfl_xor(s, 16, 64);  s  += __shfl_xor(s, 32, 64);
    qq += __shfl_xor(qq, 16, 64); qq += __shfl_xor(qq, 32, 64);
    if (lane < 16) { sm[wave * 128 + t * 16 + lane] = s; sm[wave * 128 + 64 + t * 16 + lane] = qq; }
  }
  __syncthreads();
  if (threadIdx.x < 128) {
    int which = threadIdx.x >> 6, cc = threadIdx.x & 63;
    float v = 0.f;
    for (int w = 0; w < 4; w++) v += sm[w * 128 + which * 64 + cc];
    atomicAdd(statsOut + (blockIdx.x & (NBIN - 1)) * 128 + which * 64 + cc, v);
  }
}

// ======== GEMM 2 (fused): h_s -> LReLU -> LDS -> per-node segsum -> s_e =====
// v11: 512 rows/block (two sequential 256-row chunks); wlds aliased into hs.
__global__ __launch_bounds__(256) void gemm2_kernel(
    const u16* __restrict__ hin,
    const float* __restrict__ stats1, float invE,
    const void* __restrict__ g, const void* __restrict__ b,
    const void* __restrict__ W, const void* __restrict__ c,
    int E, float* __restrict__ statsOut,
    const int* __restrict__ offs, const int* __restrict__ nodeof,
    float* __restrict__ s_e, const int* __restrict__ modep) {
  __shared__ union { u16 wlds[4096]; u16 hs[256 * 64]; } u;  // wlds dead after fold
  __shared__ u16 wpack[4096];
  __shared__ float s_s[64], s_off[64], sbias[64];
  __shared__ float sm[512];
  const int mode = *modep;
  fold_block(stats1, invE, g, b, W, c, 64, 64, mode, u.wlds, wpack, s_s, s_off, sbias);
  __syncthreads();  // wlds fully consumed before hs overwrite
  const int lane = threadIdx.x & 63, wave = threadIdx.x >> 6;
  const int q = lane >> 4, r = lane & 15;
  bf16x8 bfr[4][2];
#pragma unroll
  for (int t = 0; t < 4; t++)
#pragma unroll
    for (int h = 0; h < 2; h++)
      bfr[t][h] = *reinterpret_cast<const bf16x8*>(wpack + ((t * 2 + h) * 64 + lane) * 8);
  float bv[4];
#pragma unroll
  for (int t = 0; t < 4; t++) bv[t] = sbias[t * 16 + r];
  float s_[4] = {0, 0, 0, 0}, q_[4] = {0, 0, 0, 0};
  for (int ck = 0; ck < 2; ck++) {
    const long bbase = (long)blockIdx.x * 512 + ck * 256;
    if (bbase >= (long)E) break;
    const long wbase = bbase + wave * 64;
#pragma unroll
    for (int r4 = 0; r4 < 4; r4++) {
      const long row0 = wbase + r4 * 16;
      long e = row0 + r; if (e > E - 1) e = E - 1;
      bf16x8 a0 = ldb8(hin + e * 64 + q * 8);
      bf16x8 a1 = ldb8(hin + e * 64 + 32 + q * 8);
      floatx4 acc[4];
#pragma unroll
      for (int t = 0; t < 4; t++) {
        acc[t] = (floatx4){bv[t], bv[t], bv[t], bv[t]};
        acc[t] = mfma16(a0, bfr[t][0], acc[t]);
        acc[t] = mfma16(a1, bfr[t][1], acc[t]);
      }
      const int lbase = wave * 64 + r4 * 16;
#pragma unroll
      for (int t = 0; t < 4; t++) {
        const int colx = ((t ^ q) << 4) + r;  // XOR swizzle: conflict-free
#pragma unroll
        for (int gi = 0; gi < 4; gi++) {
          long row = row0 + q * 4 + gi;
          float v = acc[t][gi];
          v = v > 0.f ? v : 0.1f * v;
          u16 st = f2bf(v);
          u.hs[(lbase + q * 4 + gi) * 64 + colx] = st;
          if (row < E) {
            float vv = bf2f(st);
            s_[t] += vv; q_[t] += vv * vv;
          }
        }
      }
    }
    __syncthreads();  // hs visible to all waves
    // ---- segment-sum over this chunk's 256 sorted rows ----
    const long blockEnd = (bbase + 256 < (long)E) ? bbase + 256 : (long)E;
    const int first = nodeof[bbase];
    const int last  = nodeof[blockEnd - 1];
    for (int idx = first + wave; idx <= last; idx += 4) {
      int st = offs[idx], en = offs[idx + 1];
      long cs = st < bbase ? bbase : (long)st;
      long ce = (long)en > blockEnd ? blockEnd : (long)en;
      if (cs >= ce) continue;
      float acc = 0.f;
      for (long i = cs - bbase; i < ce - bbase; i++)
        acc += bf2f(u.hs[i * 64 + (lane ^ (int)(((i >> 2) & 3) << 4))]);
      if ((long)st >= bbase && (long)en <= blockEnd)
        s_e[(long)idx * 64 + lane] = acc;
      else
        atomicAdd(s_e + (long)idx * 64 + lane, acc);
    }
    __syncthreads();  // segsum done before hs overwrite by next chunk
  }
#pragma unroll
  for (int t = 0; t < 4; t++) {
    float s = s_[t], qq = q_[t];
    s  += __shfl_xor(s, 16, 64);  s  += __shfl_xor(s, 32, 64);
    qq += __shfl_xor(qq, 16, 64); qq += __shfl_xor(qq, 32, 64);
    if (lane < 16) { sm[wave * 128 + t * 16 + lane] = s; sm[wave * 128 + 64 + t * 16 + lane] = qq; }
  }
  __syncthreads();
  if (threadIdx.x < 128) {
    int which = threadIdx.x >> 6, cc = threadIdx.x & 63;
    float v = 0.f;
    for (int w = 0; w < 4; w++) v += sm[w * 128 + which * 64 + cc];
    atomicAdd(statsOut + (blockIdx.x & (NBIN - 1)) * 128 + which * 64 + cc, v);
  }
}

// ======== GEMM Agg: agg_b[n] = bf16( bf16(s_e[n]) @ W3' + deg[n]*b3' ) ======
__global__ __launch_bounds__(256) void gemmAgg_kernel(
    const float* __restrict__ s_e, const int* __restrict__ deg,
    const float* __restrict__ stats2, float invE,
    const void* __restrict__ g, const void* __restrict__ b,
    const void* __restrict__ W, const void* __restrict__ c,
    u16* __restrict__ agg_b, int N, float* __restrict__ statsOut,
    const int* __restrict__ modep) {
  __shared__ u16 wlds[4096], wpack[4096];
  __shared__ float s_s[64], s_off[64], sbias[64];
  __shared__ float sm[512];
  const int mode = *modep;
  fold_block(stats2, invE, g, b, W, c, 64, 64, mode, wlds, wpack, s_s, s_off, sbias);
  const int lane = threadIdx.x & 63, wave = threadIdx.x >> 6;
  const int q = lane >> 4, r = lane & 15;
  const long wbase = (long)blockIdx.x * 256 + wave * 64;
  bf16x8 bfr[4][2];
#pragma unroll
  for (int t = 0; t < 4; t++)
#pragma unroll
    for (int h = 0; h < 2; h++)
      bfr[t][h] = *reinterpret_cast<const bf16x8*>(wpack + ((t * 2 + h) * 64 + lane) * 8);
  float bv[4];
#pragma unroll
  for (int t = 0; t < 4; t++) bv[t] = sbias[t * 16 + r];
  float s_[4] = {0, 0, 0, 0}, q_[4] = {0, 0, 0, 0};
#pragma unroll
  for (int r4 = 0; r4 < 4; r4++) {
    const long row0 = wbase + r4 * 16;
    long m = row0 + r;
    long mm = m < N ? m : (long)N - 1;
    bf16x8 a0, a1;
    {
      const float* ap = s_e + mm * 64 + q * 8;
#pragma unroll
      for (int j = 0; j < 8; j++) a0[j] = (__bf16)ap[j];
#pragma unroll
      for (int j = 0; j < 8; j++) a1[j] = (__bf16)ap[32 + j];
    }
    floatx4 acc[4];
#pragma unroll
    for (int t = 0; t < 4; t++) {
      acc[t] = (floatx4){0.f, 0.f, 0.f, 0.f};
      acc[t] = mfma16(a0, bfr[t][0], acc[t]);
      acc[t] = mfma16(a1, bfr[t][1], acc[t]);
    }
#pragma unroll
    for (int gi = 0; gi < 4; gi++) {
      long row = row0 + q * 4 + gi;
      if (row < N) {
        float d = (float)deg[row];
#pragma unroll
        for (int t = 0; t < 4; t++) {
          float v = acc[t][gi] + d * bv[t];
          agg_b[row * 64 + t * 16 + r] = f2bf(v);
          s_[t] += v; q_[t] += v * v;
        }
      }
    }
  }
#pragma unroll
  for (int t = 0; t < 4; t++) {
    float s = s_[t], qq = q_[t];
    s  += __shfl_xor(s, 16, 64);  s  += __shfl_xor(s, 32, 64);
    qq += __shfl_xor(qq, 16, 64); qq += __shfl_xor(qq, 32, 64);
    if (lane < 16) { sm[wave * 128 + t * 16 + lane] = s; sm[wave * 128 + 64 + t * 16 + lane] = qq; }
  }
  __syncthreads();
  if (threadIdx.x < 128) {
    int which = threadIdx.x >> 6, cc = threadIdx.x & 63;
    float v = 0.f;
    for (int w = 0; w < 4; w++) v += sm[w * 128 + which * 64 + cc];
    // statsB0 [NBIN][192]: sums [0..95], sumsq [96..191]; agg = cols 32..95
    atomicAdd(statsOut + (blockIdx.x & (NBIN - 1)) * 192 + which * 96 + 32 + cc, v);
  }
}

// ======== GEMM B1: [xb, agg_b] (K=96 -> 96), LReLU, stats =================
__global__ __launch_bounds__(256) void gemmB1_kernel(
    const u16* __restrict__ xb, const u16* __restrict__ agg_b,
    const float* __restrict__ statsB0, float invN,
    const void* __restrict__ g, const void* __restrict__ b,
    const void* __restrict__ W, const void* __restrict__ c,
    u16* __restrict__ hout, int N, float* __restrict__ statsOut,
    const int* __restrict__ modep) {
  __shared__ u16 wlds[9216], wpack[9216];
  __shared__ float s_s[96], s_off[96], sbias[96];
  __shared__ float sm[768];
  const int mode = *modep;
  fold_block(statsB0, invN, g, b, W, c, 96, 96, mode, wlds, wpack, s_s, s_off, sbias);
  const int lane = threadIdx.x & 63, wave = threadIdx.x >> 6;
  const int q = lane >> 4, r = lane & 15;
  const long wbase = (long)blockIdx.x * 256 + wave * 64;
  bf16x8 bfr[6][3];
#pragma unroll
  for (int t = 0; t < 6; t++)
#pragma unroll
    for (int h = 0; h < 3; h++)
      bfr[t][h] = *reinterpret_cast<const bf16x8*>(wpack + ((t * 3 + h) * 64 + lane) * 8);
  float bv[6];
#pragma unroll
  for (int t = 0; t < 6; t++) bv[t] = sbias[t * 16 + r];
  float s_[6] = {0, 0, 0, 0, 0, 0}, q_[6] = {0, 0, 0, 0, 0, 0};
#pragma unroll
  for (int r4 = 0; r4 < 4; r4++) {
    const long row0 = wbase + r4 * 16;
    long m = row0 + r;
    long mm = m < N ? m : (long)N - 1;
    bf16x8 a0 = ldb8(xb + mm * 32 + q * 8);
    bf16x8 a1 = ldb8(agg_b + mm * 64 + q * 8);
    bf16x8 a2 = ldb8(agg_b + mm * 64 + 32 + q * 8);
    floatx4 acc[6];
#pragma unroll
    for (int t = 0; t < 6; t++) {
      acc[t] = (floatx4){bv[t], bv[t], bv[t], bv[t]};
      acc[t] = mfma16(a0, bfr[t][0], acc[t]);
      acc[t] = mfma16(a1, bfr[t][1], acc[t]);
      acc[t] = mfma16(a2, bfr[t][2], acc[t]);
    }
#pragma unroll
    for (int t = 0; t < 6; t++)
#pragma unroll
      for (int gi = 0; gi < 4; gi++) {
        long row = row0 + q * 4 + gi;
        if (row < N) {
          float v = acc[t][gi];
          v = v > 0.f ? v : 0.1f * v;
          u16 st = f2bf(v);
          hout[row * 96 + t * 16 + r] = st;
          float vv = bf2f(st);
          s_[t] += vv; q_[t] += vv * vv;
        }
      }
  }
#pragma unroll
  for (int t = 0; t < 6; t++) {
    float s = s_[t], qq = q_[t];
    s  += __shfl_xor(s, 16, 64);  s  += __shfl_xor(s, 32, 64);
    qq += __shfl_xor(qq, 16, 64); qq += __shfl_xor(qq, 32, 64);
    if (lane < 16) { sm[wave * 192 + t * 16 + lane] = s; sm[wave * 192 + 96 + t * 16 + lane] = qq; }
  }
  __syncthreads();
  if (threadIdx.x < 192) {
    int which = threadIdx.x / 96, cc = threadIdx.x % 96;
    float v = 0.f;
    for (int w = 0; w < 4; w++) v += sm[w * 192 + which * 96 + cc];
    atomicAdd(statsOut + (blockIdx.x & (NBIN - 1)) * 192 + which * 96 + cc, v);
  }
}

// ======== GEMM B2: h[N,96] -> h[N,96] in place, LReLU, stats ===============
__global__ __launch_bounds__(256) void gemmB2_kernel(
    const u16* __restrict__ hin,
    const float* __restrict__ statsB1, float invN,
    const void* __restrict__ g, const void* __restrict__ b,
    const void* __restrict__ W, const void* __restrict__ c,
    u16* __restrict__ hout, int N, float* __restrict__ statsOut,
    const int* __restrict__ modep) {
  __shared__ u16 wlds[9216], wpack[9216];
  __shared__ float s_s[96], s_off[96], sbias[96];
  __shared__ float sm[768];
  const int mode = *modep;
  fold_block(statsB1, invN, g, b, W, c, 96, 96, mode, wlds, wpack, s_s, s_off, sbias);
  const int lane = threadIdx.x & 63, wave = threadIdx.x >> 6;
  const int q = lane >> 4, r = lane & 15;
  const long wbase = (long)blockIdx.x * 256 + wave * 64;
  bf16x8 bfr[6][3];
#pragma unroll
  for (int t = 0; t < 6; t++)
#pragma unroll
    for (int h = 0; h < 3; h++)
      bfr[t][h] = *reinterpret_cast<const bf16x8*>(wpack + ((t * 3 + h) * 64 + lane) * 8);
  float bv[6];
#pragma unroll
  for (int t = 0; t < 6; t++) bv[t] = sbias[t * 16 + r];
  float s_[6] = {0, 0, 0, 0, 0, 0}, q_[6] = {0, 0, 0, 0, 0, 0};
#pragma unroll
  for (int r4 = 0; r4 < 4; r4++) {
    const long row0 = wbase + r4 * 16;
    long m = row0 + r;
    long mm = m < N ? m : (long)N - 1;
    bf16x8 a0 = ldb8(hin + mm * 96 + q * 8);
    bf16x8 a1 = ldb8(hin + mm * 96 + 32 + q * 8);
    bf16x8 a2 = ldb8(hin + mm * 96 + 64 + q * 8);
    floatx4 acc[6];
#pragma unroll
    for (int t = 0; t < 6; t++) {
      acc[t] = (floatx4){bv[t], bv[t], bv[t], bv[t]};
      acc[t] = mfma16(a0, bfr[t][0], acc[t]);
      acc[t] = mfma16(a1, bfr[t][1], acc[t]);
      acc[t] = mfma16(a2, bfr[t][2], acc[t]);
    }
#pragma unroll
    for (int t = 0; t < 6; t++)
#pragma unroll
      for (int gi = 0; gi < 4; gi++) {
        long row = row0 + q * 4 + gi;
        if (row < N) {
          float v = acc[t][gi];
          v = v > 0.f ? v : 0.1f * v;
          u16 st = f2bf(v);
          hout[row * 96 + t * 16 + r] = st;
          float vv = bf2f(st);
          s_[t] += vv; q_[t] += vv * vv;
        }
      }
  }
#pragma unroll
  for (int t = 0; t < 6; t++) {
    float s = s_[t], qq = q_[t];
    s  += __shfl_xor(s, 16, 64);  s  += __shfl_xor(s, 32, 64);
    qq += __shfl_xor(qq, 16, 64); qq += __shfl_xor(qq, 32, 64);
    if (lane < 16) { sm[wave * 192 + t * 16 + lane] = s; sm[wave * 192 + 96 + t * 16 + lane] = qq; }
  }
  __syncthreads();
  if (threadIdx.x < 192) {
    int which = threadIdx.x / 96, cc = threadIdx.x % 96;
    float v = 0.f;
    for (int w = 0; w < 4; w++) v += sm[w * 192 + which * 96 + cc];
    atomicAdd(statsOut + (blockIdx.x & (NBIN - 1)) * 192 + which * 96 + cc, v);
  }
}

// ======== GEMM B3: h[N,96] -> out[N,32], no activation =====================
__global__ __launch_bounds__(256) void gemmB3_kernel(
    const u16* __restrict__ hin,
    const float* __restrict__ statsB2, float invN,
    const void* __restrict__ g, const void* __restrict__ b,
    const void* __restrict__ W, const void* __restrict__ c,
    void* __restrict__ outv, int N, const int* __restrict__ modep) {
  __shared__ u16 wlds[3072], wpack[3072];
  __shared__ float s_s[96], s_off[96], sbias[32];
  const int mode = *modep;
  fold_block(statsB2, invN, g, b, W, c, 96, 32, mode, wlds, wpack, s_s, s_off, sbias);
  const int lane = threadIdx.x & 63, wave = threadIdx.x >> 6;
  const int q = lane >> 4, r = lane & 15;
  const long wbase = (long)blockIdx.x * 256 + wave * 64;
  bf16x8 bfr[2][3];
#pragma unroll
  for (int t = 0; t < 2; t++)
#pragma unroll
    for (int h = 0; h < 3; h++)
      bfr[t][h] = *reinterpret_cast<const bf16x8*>(wpack + ((t * 3 + h) * 64 + lane) * 8);
  float bv[2];
#pragma unroll
  for (int t = 0; t < 2; t++) bv[t] = sbias[t * 16 + r];
#pragma unroll
  for (int r4 = 0; r4 < 4; r4++) {
    const long row0 = wbase + r4 * 16;
    long m = row0 + r;
    long mm = m < N ? m : (long)N - 1;
    bf16x8 a0 = ldb8(hin + mm * 96 + q * 8);
    bf16x8 a1 = ldb8(hin + mm * 96 + 32 + q * 8);
    bf16x8 a2 = ldb8(hin + mm * 96 + 64 + q * 8);
    floatx4 acc[2];
#pragma unroll
    for (int t = 0; t < 2; t++) {
      acc[t] = (floatx4){bv[t], bv[t], bv[t], bv[t]};
      acc[t] = mfma16(a0, bfr[t][0], acc[t]);
      acc[t] = mfma16(a1, bfr[t][1], acc[t]);
      acc[t] = mfma16(a2, bfr[t][2], acc[t]);
    }
#pragma unroll
    for (int t = 0; t < 2; t++)
#pragma unroll
      for (int gi = 0; gi < 4; gi++) {
        long row = row0 + q * 4 + gi;
        if (row < N) {
          float v = acc[t][gi];
          if (mode) ((u16*)outv)[row * 32 + t * 16 + r] = f2bf(v);
          else      ((float*)outv)[row * 32 + t * 16 + r] = v;
        }
      }
  }
}

// ---------------------------------------------------------------------------
extern "C" void kernel_launch(void* const* d_in, const int* in_sizes, int n_in,
                              void* d_out, int out_size, void* d_ws,
                              size_t ws_size, hipStream_t stream) {
  const int N = in_sizes[0] / 32;
  const int E = in_sizes[2] / 32;

  const void* x    = d_in[0];
  const int*  eidx = (const int*)d_in[1];  // [2][E]: row=eidx, col=eidx+E
  const void* ea   = d_in[2];
  const void *m1_g1 = d_in[5],  *m1_b1 = d_in[6];
  const void *m1_w1 = d_in[7],  *m1_c1 = d_in[8];
  const void *m1_g2 = d_in[9],  *m1_b2 = d_in[10];
  const void *m1_w2 = d_in[11], *m1_c2 = d_in[12];
  const void *m1_g3 = d_in[13], *m1_b3 = d_in[14];
  const void *m1_w3 = d_in[15], *m1_c3 = d_in[16];
  const void *m2_g1 = d_in[17], *m2_b1 = d_in[18];
  const void *m2_w1 = d_in[19], *m2_c1 = d_in[20];
  const void *m2_g2 = d_in[21], *m2_b2 = d_in[22];
  const void *m2_w2 = d_in[23], *m2_c2 = d_in[24];
  const void *m2_g3 = d_in[25], *m2_b3 = d_in[26];
  const void *m2_w3 = d_in[27], *m2_c3 = d_in[28];

  // workspace carve (16B-aligned chunks)
  char* w = (char*)d_ws;
  int*   modep  = (int*)w;   w += 16;
  u16*   h_s    = (u16*)w;   w += (size_t)E * 64 * 2;       // 102.4 MB (sorted)
  u16*   h2b    = (u16*)w;   w += (size_t)N * 96 * 2;       //  19.2 MB
  u16*   agg_b  = (u16*)w;   w += (size_t)N * 64 * 2;       //  12.8 MB
  u16*   xb     = (u16*)w;   w += (size_t)N * 32 * 2;       //   6.4 MB
  int*   offs   = (int*)w;   w += ((size_t)N + 4) * 4;
  int*   cursor = (int*)w;   w += ((size_t)N + 4) * 4;
  int*   ipos   = (int*)w;   w += (size_t)E * 4;            //   3.2 MB
  int*   nodeof = (int*)w;   w += (size_t)E * 4;            //   3.2 MB
  int*   bsum   = (int*)w;   w += 1024 * 4;
  // zero zone: s_e + deg + odeg + all stats buffers (contiguous)
  float* s_e    = (float*)w; w += (size_t)N * 64 * 4;       //  25.6 MB
  int*   deg    = (int*)w;   w += (size_t)N * 4;
  int*   odeg   = (int*)w;   w += (size_t)N * 4;
  float* stats0 = (float*)w; w += NBIN * 128 * 4;
  float* stats1 = (float*)w; w += NBIN * 128 * 4;
  float* stats2 = (float*)w; w += NBIN * 128 * 4;
  float* statsB0= (float*)w; w += NBIN * 192 * 4;
  float* statsB1= (float*)w; w += NBIN * 192 * 4;
  float* statsB2= (float*)w; w += NBIN * 192 * 4;
  const size_t zero_bytes = (size_t)N * 64 * 4 + (size_t)N * 8 +
                            NBIN * (128 * 3 + 192 * 3) * 4;
  // bf16 copy of ea (required by v11 gemm1; ws is large enough in practice)
  const size_t eab_bytes = (size_t)E * 32 * 2;              //  51.2 MB
  u16* eab = (u16*)w;

  const int* erow = eidx;
  const int* ecol = eidx + E;
  const float invE = 1.0f / (float)E, invN = 1.0f / (float)N;
  const int gA2 = (E + 511) / 512, gB = (N + 255) / 256;
  const int nb = (N + 1023) / 1024;
  (void)eab_bytes;

  detect_kernel<<<1, 256, 0, stream>>>((const u16*)x, modep);
  hipMemsetAsync(s_e, 0, zero_bytes, stream);

  // --- counting sort of edges by destination + degree histograms ---
  count2_kernel<<<1024, 256, 0, stream>>>(erow, ecol, E, odeg, deg);
  scan1_kernel<<<nb, 1024, 0, stream>>>(deg, N, offs, bsum);
  scan2_kernel<<<1, 1024, 0, stream>>>(bsum, nb, offs, N, E);
  scan3_kernel<<<nb, 1024, 0, stream>>>(offs, bsum, N, cursor);
  scatter_kernel<<<1024, 256, 0, stream>>>(ecol, E, cursor, ipos, nodeof);

  // --- merged input stats + xb/eab conversion ---
  stats_in_kernel<<<512 + EA_BLOCKS, 256, 0, stream>>>(x, odeg, N, ea, E,
                                                       stats0, statsB0, xb, eab,
                                                       modep);

  // --- phase A: edge MLP (h written destination-sorted; folds inlined) ---
  gemm1_kernel<<<gA2, 256, 0, stream>>>(
      xb, eab, erow, ipos, stats0, invE, m1_g1, m1_b1, m1_w1, m1_c1,
      h_s, E, stats1, modep);
  gemm2_kernel<<<gA2, 256, 0, stream>>>(
      h_s, stats1, invE, m1_g2, m1_b2, m1_w2, m1_c2,
      E, stats2, offs, nodeof, s_e, modep);

  // --- aggregation GEMM ---
  gemmAgg_kernel<<<gB, 256, 0, stream>>>(
      s_e, deg, stats2, invE, m1_g3, m1_b3, m1_w3, m1_c3,
      agg_b, N, statsB0, modep);

  // --- phase B: node MLP ---
  gemmB1_kernel<<<gB, 256, 0, stream>>>(
      xb, agg_b, statsB0, invN, m2_g1, m2_b1, m2_w1, m2_c1,
      h2b, N, statsB1, modep);
  gemmB2_kernel<<<gB, 256, 0, stream>>>(
      h2b, statsB1, invN, m2_g2, m2_b2, m2_w2, m2_c2,
      h2b, N, statsB2, modep);
  gemmB3_kernel<<<gB, 256, 0, stream>>>(
      h2b, statsB2, invN, m2_g3, m2_b3, m2_w3, m2_c3,
      d_out, N, modep);
}

// Round 8
// 612.086 us; speedup vs baseline: 1.0175x; 1.0175x over previous
//
#include <hip/hip_runtime.h>

// ---------------------------------------------------------------------------
// NodeModel (GraphNet node block), MI355X / gfx950.
// v12: gemm2 fixed after v11 regression (chunk-serialization): back to 256
//   rows/block (3125 blocks), all 8 hin loads hoisted ahead of MFMA, LDS
//   packed to exactly 40960B (hs unioned with wlds+s_s/s_off/sbias; sm
//   unioned with wpack) -> 4 blocks/CU (was 3). gemm1 keeps v11's 512-row
//   double-gather (loads-first, no barriers -> did not regress).
// v10: NBIN=64 hot-line atomic fix (+146us, validated). fold vectorized (v9).
// Aggregation: h written dest-sorted (ipos), gemm2 fuses LDS segment-sum
// -> s_e; agg[n] = bf16(s_e[n]) @ W3' + deg[n]*b3' (BN affine commutes).
// MFMA layouts (verified): A[m=lane&15][k=(lane>>4)*8+j],
//   B[k=(lane>>4)*8+j][n=lane&15], C/D: col=lane&15, row=(lane>>4)*4+reg.
// ---------------------------------------------------------------------------

typedef unsigned short u16;
typedef __bf16  bf16x8  __attribute__((ext_vector_type(8)));
typedef float   floatx4 __attribute__((ext_vector_type(4)));

#define NBIN 64
#define EA_BLOCKS 1024

__device__ __forceinline__ float bf2f(u16 u) {
  union { float f; unsigned int i; } v; v.i = ((unsigned int)u) << 16; return v.f;
}
__device__ __forceinline__ u16 f2bf(float f) {
  union { float f; unsigned int i; } v; v.f = f;
  unsigned int x = v.i;
  return (u16)((x + 0x7fffu + ((x >> 16) & 1u)) >> 16);  // RNE
}
__device__ __forceinline__ bf16x8 ldb8(const u16* p) {
  return *reinterpret_cast<const bf16x8*>(p);
}
__device__ __forceinline__ floatx4 mfma16(bf16x8 a, bf16x8 b, floatx4 c) {
  return __builtin_amdgcn_mfma_f32_16x16x32_bf16(a, b, c, 0, 0, 0);
}
// mode: 0 = float32, 1 = bf16
__device__ __forceinline__ float loadf(const void* p, long idx, int mode) {
  return mode ? bf2f(((const u16*)p)[idx]) : ((const float*)p)[idx];
}
__device__ __forceinline__ bf16x8 load8(const void* p, long idx, int mode) {
  if (mode) return ldb8((const u16*)p + idx);
  const float* f = (const float*)p + idx;
  bf16x8 r;
#pragma unroll
  for (int j = 0; j < 8; j++) r[j] = (__bf16)f[j];
  return r;
}

// ---------------- per-block BN fold: stats -> scale/offset -> packed W+bias
// wlds: K*OUT u16 LDS, wpack: same size, s_s/s_off: K floats, sbias: OUT.
// v9: staging and repack vectorized to 16B ops (was scalar 2B).
__device__ __forceinline__ void fold_block(
    const float* __restrict__ stats, float inv_rows,
    const void* __restrict__ g, const void* __restrict__ b,
    const void* __restrict__ W, const void* __restrict__ c,
    int K, int OUT, int mode,
    u16* wlds, u16* wpack, float* s_s, float* s_off, float* sbias) {
  const int tid = threadIdx.x;
  const int tot8 = (K * OUT) >> 3;  // always divisible by 8
  for (int i = tid; i < tot8; i += 256) {
    bf16x8 o;
    if (mode) {
      o = ldb8((const u16*)W + (size_t)i * 8);
    } else {
      const float* f = (const float*)W + (size_t)i * 8;
      float4 a = *(const float4*)f;
      float4 d = *(const float4*)(f + 4);
      o[0] = (__bf16)a.x; o[1] = (__bf16)a.y; o[2] = (__bf16)a.z; o[3] = (__bf16)a.w;
      o[4] = (__bf16)d.x; o[5] = (__bf16)d.y; o[6] = (__bf16)d.z; o[7] = (__bf16)d.w;
    }
    *reinterpret_cast<bf16x8*>(wlds + (size_t)i * 8) = o;
  }
  if (tid < K) {
    float sum = 0.f, sq = 0.f;
    for (int p = 0; p < NBIN; p++) {
      sum += stats[p * 2 * K + tid];
      sq  += stats[p * 2 * K + K + tid];
    }
    float m = sum * inv_rows, var = sq * inv_rows - m * m;
    float s = loadf(g, tid, mode) * rsqrtf(var + 1e-5f);
    s_s[tid] = s;
    s_off[tid] = loadf(b, tid, mode) - m * s;
  }
  __syncthreads();
  if (tid < OUT) {
    float acc = loadf(c, tid, mode);
    for (int k = 0; k < K; k++) acc += s_off[k] * bf2f(wlds[k * OUT + tid]);
    sbias[tid] = acc;
  }
  const int H = K >> 5, T = OUT >> 4;
  const int tot8p = T * H * 64;  // (T*H*512)/8
  for (int i8 = tid; i8 < tot8p; i8 += 256) {
    int lane = i8 & 63, th = i8 >> 6;
    int h = th % H, t = th / H;
    int kb = h * 32 + ((lane >> 4) << 3);
    int n = (t << 4) + (lane & 15);
    bf16x8 o;
#pragma unroll
    for (int j = 0; j < 8; j++)
      o[j] = (__bf16)(s_s[kb + j] * bf2f(wlds[(kb + j) * OUT + n]));
    *reinterpret_cast<bf16x8*>(wpack + (size_t)i8 * 8) = o;
  }
  __syncthreads();
}

// ---------------- dtype detection
__global__ void detect_kernel(const u16* __restrict__ x, int* __restrict__ modep) {
  __shared__ int cnt;
  if (threadIdx.x == 0) cnt = 0;
  __syncthreads();
  int weird = 0;
  for (int i = threadIdx.x; i < 1024; i += blockDim.x) {
    unsigned e = (x[i] >> 7) & 0xFFu;
    if (e == 0xFFu || e >= 0x90u || (e != 0u && e < 0x60u)) weird++;
  }
  atomicAdd(&cnt, weird);
  __syncthreads();
  if (threadIdx.x == 0) *modep = (cnt > 128) ? 0 : 1;
}

// ================= counting sort of edges by destination ====================
__global__ void count2_kernel(const int* __restrict__ row, const int* __restrict__ col,
                              int E, int* __restrict__ odeg, int* __restrict__ deg) {
  for (int e = blockIdx.x * blockDim.x + threadIdx.x; e < E;
       e += gridDim.x * blockDim.x) {
    atomicAdd(&odeg[row[e]], 1);
    atomicAdd(&deg[col[e]], 1);
  }
}

__global__ void scan1_kernel(const int* __restrict__ deg, int n,
                             int* __restrict__ excl, int* __restrict__ bsum) {
  __shared__ int tmp[2][1024];
  const int tid = threadIdx.x;
  const int i = blockIdx.x * 1024 + tid;
  int v = (i < n) ? deg[i] : 0;
  tmp[0][tid] = v;
  __syncthreads();
  int src = 0;
  for (int off = 1; off < 1024; off <<= 1) {
    int t = tmp[src][tid];
    if (tid >= off) t += tmp[src][tid - off];
    tmp[1 - src][tid] = t;
    src = 1 - src;
    __syncthreads();
  }
  if (i < n) excl[i] = tmp[src][tid] - v;
  if (tid == 1023) bsum[blockIdx.x] = tmp[src][1023];
}

// parallel exclusive scan of up to 1024 block sums
__global__ void scan2_kernel(int* __restrict__ bsum, int nb,
                             int* __restrict__ offsets, int N, int E) {
  __shared__ int tmp[2][1024];
  const int tid = threadIdx.x;
  int v = (tid < nb) ? bsum[tid] : 0;
  tmp[0][tid] = v;
  __syncthreads();
  int src = 0;
  for (int off = 1; off < 1024; off <<= 1) {
    int t = tmp[src][tid];
    if (tid >= off) t += tmp[src][tid - off];
    tmp[1 - src][tid] = t;
    src = 1 - src;
    __syncthreads();
  }
  if (tid < nb) bsum[tid] = tmp[src][tid] - v;
  if (tid == 0) offsets[N] = E;
}

__global__ void scan3_kernel(int* __restrict__ offsets, const int* __restrict__ bsum,
                             int n, int* __restrict__ cursor) {
  int i = blockIdx.x * 1024 + threadIdx.x;
  if (i < n) {
    int v = offsets[i] + bsum[blockIdx.x];
    offsets[i] = v;
    cursor[i] = v;
  }
}

__global__ void scatter_kernel(const int* __restrict__ col, int E,
                               int* __restrict__ cursor, int* __restrict__ ipos,
                               int* __restrict__ nodeof) {
  for (int e = blockIdx.x * blockDim.x + threadIdx.x; e < E;
       e += gridDim.x * blockDim.x) {
    int d = col[e];
    int pos = atomicAdd(&cursor[d], 1);
    ipos[e] = pos;
    nodeof[pos] = d;
  }
}

// ---------------- merged input stats:
// blocks [0,512): x pass -> unweighted stats (statsB0 c0..31), odeg-weighted
//   (stats0 c0..31), and xb = bf16(x).
// blocks [512,512+EA_BLOCKS): ea streaming pass -> stats0 c32..63, linear eab.
// v10: ea-pass cross-wave LDS reduction -> 64 atomics/block (was 256).
__global__ void stats_in_kernel(const void* __restrict__ x,
                                const int* __restrict__ odeg, int N,
                                const void* __restrict__ ea, int E,
                                float* __restrict__ stats0,
                                float* __restrict__ statsB0,
                                u16* __restrict__ xb, u16* __restrict__ eab,
                                const int* __restrict__ modep) {
  const int mode = *modep;
  if (blockIdx.x < 512) {
    const int c = threadIdx.x & 31, rs = threadIdx.x >> 5;  // 8 rows/iter
    float s = 0.f, q = 0.f, ws = 0.f, wq = 0.f;
    for (long rr = (long)blockIdx.x * 8 + rs; rr < N; rr += 512 * 8) {
      float v = loadf(x, rr * 32 + c, mode);
      float w = (float)odeg[rr];
      xb[rr * 32 + c] = f2bf(v);
      s += v; q += v * v; ws += w * v; wq += w * v * v;
    }
    __shared__ float sm[4][256];
    sm[0][threadIdx.x] = s;  sm[1][threadIdx.x] = q;
    sm[2][threadIdx.x] = ws; sm[3][threadIdx.x] = wq;
    __syncthreads();
    if (threadIdx.x < 32) {
      for (int i = 1; i < 8; i++) {
        s  += sm[0][i * 32 + c]; q  += sm[1][i * 32 + c];
        ws += sm[2][i * 32 + c]; wq += sm[3][i * 32 + c];
      }
      const int bin = blockIdx.x & (NBIN - 1);
      atomicAdd(statsB0 + bin * 192 + c, s);
      atomicAdd(statsB0 + bin * 192 + 96 + c, q);
      atomicAdd(stats0 + bin * 128 + c, ws);
      atomicAdd(stats0 + bin * 128 + 64 + c, wq);
    }
  } else {
    const int bid = blockIdx.x - 512;                        // 0..EA_BLOCKS-1
    const int cg = threadIdx.x & 3, rsub = threadIdx.x >> 2;  // 64 rows/iter
    const int lane = threadIdx.x & 63, wave = threadIdx.x >> 6;
    float s[8], q[8];
#pragma unroll
    for (int j = 0; j < 8; j++) { s[j] = 0.f; q[j] = 0.f; }
    for (long rr = (long)bid * 64 + rsub; rr < E; rr += (long)EA_BLOCKS * 64) {
      float f0[8];
      if (mode) {
        bf16x8 v = ldb8((const u16*)ea + rr * 32 + cg * 8);
#pragma unroll
        for (int j = 0; j < 8; j++) f0[j] = (float)v[j];
      } else {
        const float* p = (const float*)ea + rr * 32 + cg * 8;
        float4 a = *(const float4*)p;
        float4 b = *(const float4*)(p + 4);
        f0[0]=a.x; f0[1]=a.y; f0[2]=a.z; f0[3]=a.w;
        f0[4]=b.x; f0[5]=b.y; f0[6]=b.z; f0[7]=b.w;
      }
      if (eab) {
        bf16x8 o;
#pragma unroll
        for (int j = 0; j < 8; j++) o[j] = (__bf16)f0[j];
        *reinterpret_cast<bf16x8*>(eab + rr * 32 + cg * 8) = o;
      }
#pragma unroll
      for (int j = 0; j < 8; j++) { s[j] += f0[j]; q[j] += f0[j] * f0[j]; }
    }
#pragma unroll
    for (int st = 4; st < 64; st <<= 1) {
#pragma unroll
      for (int j = 0; j < 8; j++) {
        s[j] += __shfl_xor(s[j], st, 64);
        q[j] += __shfl_xor(q[j], st, 64);
      }
    }
    // cross-wave LDS reduction: one atomic set per BLOCK (64 adds), not per wave
    __shared__ float red[4][64];
    if (lane < 4) {
#pragma unroll
      for (int j = 0; j < 8; j++) {
        red[wave][lane * 8 + j] = s[j];
        red[wave][32 + lane * 8 + j] = q[j];
      }
    }
    __syncthreads();
    if (wave == 0 && lane < 4) {
      float* o = stats0 + (blockIdx.x & (NBIN - 1)) * 128;
#pragma unroll
      for (int j = 0; j < 8; j++) {
        float ss = red[0][lane * 8 + j] + red[1][lane * 8 + j] +
                   red[2][lane * 8 + j] + red[3][lane * 8 + j];
        float qq = red[0][32 + lane * 8 + j] + red[1][32 + lane * 8 + j] +
                   red[2][32 + lane * 8 + j] + red[3][32 + lane * 8 + j];
        atomicAdd(o + 32 + lane * 8 + j, ss);
        atomicAdd(o + 96 + lane * 8 + j, qq);
      }
    }
  }
}

// ======== GEMM 1: [xb[row[e]], ea[e]] -> h (dest-sorted), LReLU, stats ======
// v11: 512 rows/block; both chunks' gathers issued up-front (2x MLP).
__global__ __launch_bounds__(256) void gemm1_kernel(
    const u16* __restrict__ xb, const u16* __restrict__ eab,
    const int* __restrict__ erow, const int* __restrict__ ipos,
    const float* __restrict__ stats0, float invE,
    const void* __restrict__ g, const void* __restrict__ b,
    const void* __restrict__ W, const void* __restrict__ c,
    u16* __restrict__ hout, int E,
    float* __restrict__ statsOut, const int* __restrict__ modep) {
  __shared__ u16 wlds[4096], wpack[4096];
  __shared__ float s_s[64], s_off[64], sbias[64];
  __shared__ float sm[512];
  const int mode = *modep;
  fold_block(stats0, invE, g, b, W, c, 64, 64, mode, wlds, wpack, s_s, s_off, sbias);
  const int lane = threadIdx.x & 63, wave = threadIdx.x >> 6;
  const int q = lane >> 4, r = lane & 15;
  const long cb0 = (long)blockIdx.x * 512 + wave * 64;
  const long cb1 = cb0 + 256;
  bf16x8 bfr[4][2];
#pragma unroll
  for (int t = 0; t < 4; t++)
#pragma unroll
    for (int h = 0; h < 2; h++)
      bfr[t][h] = *reinterpret_cast<const bf16x8*>(wpack + ((t * 2 + h) * 64 + lane) * 8);
  float bv[4];
#pragma unroll
  for (int t = 0; t < 4; t++) bv[t] = sbias[t * 16 + r];
  // gather BOTH chunks up-front (16x 16B loads in flight per thread)
  bf16x8 A00[4], A10[4], A01[4], A11[4];
  int P0[4][4], P1[4][4];
#pragma unroll
  for (int r4 = 0; r4 < 4; r4++) {
    long e = cb0 + r4 * 16 + r; if (e > E - 1) e = E - 1;
    int src = erow[e];
    A00[r4] = ldb8(xb + (long)src * 32 + q * 8);
    A10[r4] = ldb8(eab + e * 32 + q * 8);
#pragma unroll
    for (int gi = 0; gi < 4; gi++) {
      long row = cb0 + r4 * 16 + q * 4 + gi;
      P0[r4][gi] = (row < E) ? ipos[row] : -1;
    }
  }
#pragma unroll
  for (int r4 = 0; r4 < 4; r4++) {
    long e = cb1 + r4 * 16 + r; if (e > E - 1) e = E - 1;
    int src = erow[e];
    A01[r4] = ldb8(xb + (long)src * 32 + q * 8);
    A11[r4] = ldb8(eab + e * 32 + q * 8);
#pragma unroll
    for (int gi = 0; gi < 4; gi++) {
      long row = cb1 + r4 * 16 + q * 4 + gi;
      P1[r4][gi] = (row < E) ? ipos[row] : -1;
    }
  }
  float s_[4] = {0, 0, 0, 0}, q_[4] = {0, 0, 0, 0};
  // compute chunk 0
#pragma unroll
  for (int r4 = 0; r4 < 4; r4++) {
    floatx4 acc[4];
#pragma unroll
    for (int t = 0; t < 4; t++) {
      acc[t] = (floatx4){bv[t], bv[t], bv[t], bv[t]};
      acc[t] = mfma16(A00[r4], bfr[t][0], acc[t]);
      acc[t] = mfma16(A10[r4], bfr[t][1], acc[t]);
    }
#pragma unroll
    for (int gi = 0; gi < 4; gi++) {
      long p = P0[r4][gi];
      if (p >= 0) {
#pragma unroll
        for (int t = 0; t < 4; t++) {
          float v = acc[t][gi];
          v = v > 0.f ? v : 0.1f * v;
          u16 st = f2bf(v);
          hout[p * 64 + t * 16 + r] = st;
          float vv = bf2f(st);
          s_[t] += vv; q_[t] += vv * vv;
        }
      }
    }
  }
  // compute chunk 1
#pragma unroll
  for (int r4 = 0; r4 < 4; r4++) {
    floatx4 acc[4];
#pragma unroll
    for (int t = 0; t < 4; t++) {
      acc[t] = (floatx4){bv[t], bv[t], bv[t], bv[t]};
      acc[t] = mfma16(A01[r4], bfr[t][0], acc[t]);
      acc[t] = mfma16(A11[r4], bfr[t][1], acc[t]);
    }
#pragma unroll
    for (int gi = 0; gi < 4; gi++) {
      long p = P1[r4][gi];
      if (p >= 0) {
#pragma unroll
        for (int t = 0; t < 4; t++) {
          float v = acc[t][gi];
          v = v > 0.f ? v : 0.1f * v;
          u16 st = f2bf(v);
          hout[p * 64 + t * 16 + r] = st;
          float vv = bf2f(st);
          s_[t] += vv; q_[t] += vv * vv;
        }
      }
    }
  }
#pragma unroll
  for (int t = 0; t < 4; t++) {
    float s = s_[t], qq = q_[t];
    s  += __shfl_xor(s, 16, 64);  s  += __shfl_xor(s, 32, 64);
    qq += __shfl_xor(qq, 16, 64); qq += __shfl_xor(qq, 32, 64);
    if (lane < 16) { sm[wave * 128 + t * 16 + lane] = s; sm[wave * 128 + 64 + t * 16 + lane] = qq; }
  }
  __syncthreads();
  if (threadIdx.x < 128) {
    int which = threadIdx.x >> 6, cc = threadIdx.x & 63;
    float v = 0.f;
    for (int w = 0; w < 4; w++) v += sm[w * 128 + which * 64 + cc];
    atomicAdd(statsOut + (blockIdx.x & (NBIN - 1)) * 128 + which * 64 + cc, v);
  }
}

// ======== GEMM 2 (fused): h_s -> LReLU -> LDS -> per-node segsum -> s_e =====
// v12: 256 rows/block (3125 blocks); hin loads hoisted; LDS packed to 40960B
//   (hs aliases wlds+s_s/s_off/sbias; sm aliases wpack) -> 4 blocks/CU.
__global__ __launch_bounds__(256) void gemm2_kernel(
    const u16* __restrict__ hin,
    const float* __restrict__ stats1, float invE,
    const void* __restrict__ g, const void* __restrict__ b,
    const void* __restrict__ W, const void* __restrict__ c,
    int E, float* __restrict__ statsOut,
    const int* __restrict__ offs, const int* __restrict__ nodeof,
    float* __restrict__ s_e, const int* __restrict__ modep) {
  __shared__ union {
    struct { u16 wlds[4096]; float s_s[64]; float s_off[64]; float sbias[64]; } f;
    u16 hs[256 * 64];
  } uA;                                   // 32 KB
  __shared__ union { u16 wpack[4096]; float sm[512]; } uB;  // 8 KB
  const int mode = *modep;
  fold_block(stats1, invE, g, b, W, c, 64, 64, mode,
             uA.f.wlds, uB.wpack, uA.f.s_s, uA.f.s_off, uA.f.sbias);
  const int lane = threadIdx.x & 63, wave = threadIdx.x >> 6;
  const int q = lane >> 4, r = lane & 15;
  const long bbase = (long)blockIdx.x * 256;
  const long wbase = bbase + wave * 64;
  bf16x8 bfr[4][2];
#pragma unroll
  for (int t = 0; t < 4; t++)
#pragma unroll
    for (int h = 0; h < 2; h++)
      bfr[t][h] = *reinterpret_cast<const bf16x8*>(uB.wpack + ((t * 2 + h) * 64 + lane) * 8);
  float bv[4];
#pragma unroll
  for (int t = 0; t < 4; t++) bv[t] = uA.f.sbias[t * 16 + r];
  __syncthreads();  // all reads of wlds/sbias region done before hs overwrite
  // hoisted loads: all 8x16B in flight before compute
  bf16x8 A0[4], A1[4];
#pragma unroll
  for (int r4 = 0; r4 < 4; r4++) {
    long e = wbase + r4 * 16 + r; if (e > E - 1) e = E - 1;
    A0[r4] = ldb8(hin + e * 64 + q * 8);
    A1[r4] = ldb8(hin + e * 64 + 32 + q * 8);
  }
  float s_[4] = {0, 0, 0, 0}, q_[4] = {0, 0, 0, 0};
#pragma unroll
  for (int r4 = 0; r4 < 4; r4++) {
    const long row0 = wbase + r4 * 16;
    floatx4 acc[4];
#pragma unroll
    for (int t = 0; t < 4; t++) {
      acc[t] = (floatx4){bv[t], bv[t], bv[t], bv[t]};
      acc[t] = mfma16(A0[r4], bfr[t][0], acc[t]);
      acc[t] = mfma16(A1[r4], bfr[t][1], acc[t]);
    }
    const int lbase = wave * 64 + r4 * 16;
#pragma unroll
    for (int t = 0; t < 4; t++) {
      const int colx = ((t ^ q) << 4) + r;  // XOR swizzle: conflict-free
#pragma unroll
      for (int gi = 0; gi < 4; gi++) {
        long row = row0 + q * 4 + gi;
        float v = acc[t][gi];
        v = v > 0.f ? v : 0.1f * v;
        u16 st = f2bf(v);
        uA.hs[(lbase + q * 4 + gi) * 64 + colx] = st;
        if (row < E) {
          float vv = bf2f(st);
          s_[t] += vv; q_[t] += vv * vv;
        }
      }
    }
  }
  __syncthreads();  // hs visible to all waves
  // ---- segment-sum over this block's 256 sorted rows ----
  const long blockEnd = (bbase + 256 < (long)E) ? bbase + 256 : (long)E;
  const int first = nodeof[bbase];
  const int last  = nodeof[blockEnd - 1];
  for (int idx = first + wave; idx <= last; idx += 4) {
    int st = offs[idx], en = offs[idx + 1];
    long cs = st < bbase ? bbase : (long)st;
    long ce = (long)en > blockEnd ? blockEnd : (long)en;
    if (cs >= ce) continue;
    float acc = 0.f;
    for (long i = cs - bbase; i < ce - bbase; i++)
      acc += bf2f(uA.hs[i * 64 + (lane ^ (int)(((i >> 2) & 3) << 4))]);
    if ((long)st >= bbase && (long)en <= blockEnd)
      s_e[(long)idx * 64 + lane] = acc;
    else
      atomicAdd(s_e + (long)idx * 64 + lane, acc);
  }
  __syncthreads();  // segsum reads of hs done; wpack reads long done -> sm ok
#pragma unroll
  for (int t = 0; t < 4; t++) {
    float s = s_[t], qq = q_[t];
    s  += __shfl_xor(s, 16, 64);  s  += __shfl_xor(s, 32, 64);
    qq += __shfl_xor(qq, 16, 64); qq += __shfl_xor(qq, 32, 64);
    if (lane < 16) { uB.sm[wave * 128 + t * 16 + lane] = s; uB.sm[wave * 128 + 64 + t * 16 + lane] = qq; }
  }
  __syncthreads();
  if (threadIdx.x < 128) {
    int which = threadIdx.x >> 6, cc = threadIdx.x & 63;
    float v = 0.f;
    for (int w = 0; w < 4; w++) v += uB.sm[w * 128 + which * 64 + cc];
    atomicAdd(statsOut + (blockIdx.x & (NBIN - 1)) * 128 + which * 64 + cc, v);
  }
}

// ======== GEMM Agg: agg_b[n] = bf16( bf16(s_e[n]) @ W3' + deg[n]*b3' ) ======
__global__ __launch_bounds__(256) void gemmAgg_kernel(
    const float* __restrict__ s_e, const int* __restrict__ deg,
    const float* __restrict__ stats2, float invE,
    const void* __restrict__ g, const void* __restrict__ b,
    const void* __restrict__ W, const void* __restrict__ c,
    u16* __restrict__ agg_b, int N, float* __restrict__ statsOut,
    const int* __restrict__ modep) {
  __shared__ u16 wlds[4096], wpack[4096];
  __shared__ float s_s[64], s_off[64], sbias[64];
  __shared__ float sm[512];
  const int mode = *modep;
  fold_block(stats2, invE, g, b, W, c, 64, 64, mode, wlds, wpack, s_s, s_off, sbias);
  const int lane = threadIdx.x & 63, wave = threadIdx.x >> 6;
  const int q = lane >> 4, r = lane & 15;
  const long wbase = (long)blockIdx.x * 256 + wave * 64;
  bf16x8 bfr[4][2];
#pragma unroll
  for (int t = 0; t < 4; t++)
#pragma unroll
    for (int h = 0; h < 2; h++)
      bfr[t][h] = *reinterpret_cast<const bf16x8*>(wpack + ((t * 2 + h) * 64 + lane) * 8);
  float bv[4];
#pragma unroll
  for (int t = 0; t < 4; t++) bv[t] = sbias[t * 16 + r];
  float s_[4] = {0, 0, 0, 0}, q_[4] = {0, 0, 0, 0};
#pragma unroll
  for (int r4 = 0; r4 < 4; r4++) {
    const long row0 = wbase + r4 * 16;
    long m = row0 + r;
    long mm = m < N ? m : (long)N - 1;
    bf16x8 a0, a1;
    {
      const float* ap = s_e + mm * 64 + q * 8;
#pragma unroll
      for (int j = 0; j < 8; j++) a0[j] = (__bf16)ap[j];
#pragma unroll
      for (int j = 0; j < 8; j++) a1[j] = (__bf16)ap[32 + j];
    }
    floatx4 acc[4];
#pragma unroll
    for (int t = 0; t < 4; t++) {
      acc[t] = (floatx4){0.f, 0.f, 0.f, 0.f};
      acc[t] = mfma16(a0, bfr[t][0], acc[t]);
      acc[t] = mfma16(a1, bfr[t][1], acc[t]);
    }
#pragma unroll
    for (int gi = 0; gi < 4; gi++) {
      long row = row0 + q * 4 + gi;
      if (row < N) {
        float d = (float)deg[row];
#pragma unroll
        for (int t = 0; t < 4; t++) {
          float v = acc[t][gi] + d * bv[t];
          agg_b[row * 64 + t * 16 + r] = f2bf(v);
          s_[t] += v; q_[t] += v * v;
        }
      }
    }
  }
#pragma unroll
  for (int t = 0; t < 4; t++) {
    float s = s_[t], qq = q_[t];
    s  += __shfl_xor(s, 16, 64);  s  += __shfl_xor(s, 32, 64);
    qq += __shfl_xor(qq, 16, 64); qq += __shfl_xor(qq, 32, 64);
    if (lane < 16) { sm[wave * 128 + t * 16 + lane] = s; sm[wave * 128 + 64 + t * 16 + lane] = qq; }
  }
  __syncthreads();
  if (threadIdx.x < 128) {
    int which = threadIdx.x >> 6, cc = threadIdx.x & 63;
    float v = 0.f;
    for (int w = 0; w < 4; w++) v += sm[w * 128 + which * 64 + cc];
    // statsB0 [NBIN][192]: sums [0..95], sumsq [96..191]; agg = cols 32..95
    atomicAdd(statsOut + (blockIdx.x & (NBIN - 1)) * 192 + which * 96 + 32 + cc, v);
  }
}

// ======== GEMM B1: [xb, agg_b] (K=96 -> 96), LReLU, stats =================
__global__ __launch_bounds__(256) void gemmB1_kernel(
    const u16* __restrict__ xb, const u16* __restrict__ agg_b,
    const float* __restrict__ statsB0, float invN,
    const void* __restrict__ g, const void* __restrict__ b,
    const void* __restrict__ W, const void* __restrict__ c,
    u16* __restrict__ hout, int N, float* __restrict__ statsOut,
    const int* __restrict__ modep) {
  __shared__ u16 wlds[9216], wpack[9216];
  __shared__ float s_s[96], s_off[96], sbias[96];
  __shared__ float sm[768];
  const int mode = *modep;
  fold_block(statsB0, invN, g, b, W, c, 96, 96, mode, wlds, wpack, s_s, s_off, sbias);
  const int lane = threadIdx.x & 63, wave = threadIdx.x >> 6;
  const int q = lane >> 4, r = lane & 15;
  const long wbase = (long)blockIdx.x * 256 + wave * 64;
  bf16x8 bfr[6][3];
#pragma unroll
  for (int t = 0; t < 6; t++)
#pragma unroll
    for (int h = 0; h < 3; h++)
      bfr[t][h] = *reinterpret_cast<const bf16x8*>(wpack + ((t * 3 + h) * 64 + lane) * 8);
  float bv[6];
#pragma unroll
  for (int t = 0; t < 6; t++) bv[t] = sbias[t * 16 + r];
  float s_[6] = {0, 0, 0, 0, 0, 0}, q_[6] = {0, 0, 0, 0, 0, 0};
#pragma unroll
  for (int r4 = 0; r4 < 4; r4++) {
    const long row0 = wbase + r4 * 16;
    long m = row0 + r;
    long mm = m < N ? m : (long)N - 1;
    bf16x8 a0 = ldb8(xb + mm * 32 + q * 8);
    bf16x8 a1 = ldb8(agg_b + mm * 64 + q * 8);
    bf16x8 a2 = ldb8(agg_b + mm * 64 + 32 + q * 8);
    floatx4 acc[6];
#pragma unroll
    for (int t = 0; t < 6; t++) {
      acc[t] = (floatx4){bv[t], bv[t], bv[t], bv[t]};
      acc[t] = mfma16(a0, bfr[t][0], acc[t]);
      acc[t] = mfma16(a1, bfr[t][1], acc[t]);
      acc[t] = mfma16(a2, bfr[t][2], acc[t]);
    }
#pragma unroll
    for (int t = 0; t < 6; t++)
#pragma unroll
      for (int gi = 0; gi < 4; gi++) {
        long row = row0 + q * 4 + gi;
        if (row < N) {
          float v = acc[t][gi];
          v = v > 0.f ? v : 0.1f * v;
          u16 st = f2bf(v);
          hout[row * 96 + t * 16 + r] = st;
          float vv = bf2f(st);
          s_[t] += vv; q_[t] += vv * vv;
        }
      }
  }
#pragma unroll
  for (int t = 0; t < 6; t++) {
    float s = s_[t], qq = q_[t];
    s  += __shfl_xor(s, 16, 64);  s  += __shfl_xor(s, 32, 64);
    qq += __shfl_xor(qq, 16, 64); qq += __shfl_xor(qq, 32, 64);
    if (lane < 16) { sm[wave * 192 + t * 16 + lane] = s; sm[wave * 192 + 96 + t * 16 + lane] = qq; }
  }
  __syncthreads();
  if (threadIdx.x < 192) {
    int which = threadIdx.x / 96, cc = threadIdx.x % 96;
    float v = 0.f;
    for (int w = 0; w < 4; w++) v += sm[w * 192 + which * 96 + cc];
    atomicAdd(statsOut + (blockIdx.x & (NBIN - 1)) * 192 + which * 96 + cc, v);
  }
}

// ======== GEMM B2: h[N,96] -> h[N,96] in place, LReLU, stats ===============
__global__ __launch_bounds__(256) void gemmB2_kernel(
    const u16* __restrict__ hin,
    const float* __restrict__ statsB1, float invN,
    const void* __restrict__ g, const void* __restrict__ b,
    const void* __restrict__ W, const void* __restrict__ c,
    u16* __restrict__ hout, int N, float* __restrict__ statsOut,
    const int* __restrict__ modep) {
  __shared__ u16 wlds[9216], wpack[9216];
  __shared__ float s_s[96], s_off[96], sbias[96];
  __shared__ float sm[768];
  const int mode = *modep;
  fold_block(statsB1, invN, g, b, W, c, 96, 96, mode, wlds, wpack, s_s, s_off, sbias);
  const int lane = threadIdx.x & 63, wave = threadIdx.x >> 6;
  const int q = lane >> 4, r = lane & 15;
  const long wbase = (long)blockIdx.x * 256 + wave * 64;
  bf16x8 bfr[6][3];
#pragma unroll
  for (int t = 0; t < 6; t++)
#pragma unroll
    for (int h = 0; h < 3; h++)
      bfr[t][h] = *reinterpret_cast<const bf16x8*>(wpack + ((t * 3 + h) * 64 + lane) * 8);
  float bv[6];
#pragma unroll
  for (int t = 0; t < 6; t++) bv[t] = sbias[t * 16 + r];
  float s_[6] = {0, 0, 0, 0, 0, 0}, q_[6] = {0, 0, 0, 0, 0, 0};
#pragma unroll
  for (int r4 = 0; r4 < 4; r4++) {
    const long row0 = wbase + r4 * 16;
    long m = row0 + r;
    long mm = m < N ? m : (long)N - 1;
    bf16x8 a0 = ldb8(hin + mm * 96 + q * 8);
    bf16x8 a1 = ldb8(hin + mm * 96 + 32 + q * 8);
    bf16x8 a2 = ldb8(hin + mm * 96 + 64 + q * 8);
    floatx4 acc[6];
#pragma unroll
    for (int t = 0; t < 6; t++) {
      acc[t] = (floatx4){bv[t], bv[t], bv[t], bv[t]};
      acc[t] = mfma16(a0, bfr[t][0], acc[t]);
      acc[t] = mfma16(a1, bfr[t][1], acc[t]);
      acc[t] = mfma16(a2, bfr[t][2], acc[t]);
    }
#pragma unroll
    for (int t = 0; t < 6; t++)
#pragma unroll
      for (int gi = 0; gi < 4; gi++) {
        long row = row0 + q * 4 + gi;
        if (row < N) {
          float v = acc[t][gi];
          v = v > 0.f ? v : 0.1f * v;
          u16 st = f2bf(v);
          hout[row * 96 + t * 16 + r] = st;
          float vv = bf2f(st);
          s_[t] += vv; q_[t] += vv * vv;
        }
      }
  }
#pragma unroll
  for (int t = 0; t < 6; t++) {
    float s = s_[t], qq = q_[t];
    s  += __shfl_xor(s, 16, 64);  s  += __shfl_xor(s, 32, 64);
    qq += __shfl_xor(qq, 16, 64); qq += __shfl_xor(qq, 32, 64);
    if (lane < 16) { sm[wave * 192 + t * 16 + lane] = s; sm[wave * 192 + 96 + t * 16 + lane] = qq; }
  }
  __syncthreads();
  if (threadIdx.x < 192) {
    int which = threadIdx.x / 96, cc = threadIdx.x % 96;
    float v = 0.f;
    for (int w = 0; w < 4; w++) v += sm[w * 192 + which * 96 + cc];
    atomicAdd(statsOut + (blockIdx.x & (NBIN - 1)) * 192 + which * 96 + cc, v);
  }
}

// ======== GEMM B3: h[N,96] -> out[N,32], no activation =====================
__global__ __launch_bounds__(256) void gemmB3_kernel(
    const u16* __restrict__ hin,
    const float* __restrict__ statsB2, float invN,
    const void* __restrict__ g, const void* __restrict__ b,
    const void* __restrict__ W, const void* __restrict__ c,
    void* __restrict__ outv, int N, const int* __restrict__ modep) {
  __shared__ u16 wlds[3072], wpack[3072];
  __shared__ float s_s[96], s_off[96], sbias[32];
  const int mode = *modep;
  fold_block(statsB2, invN, g, b, W, c, 96, 32, mode, wlds, wpack, s_s, s_off, sbias);
  const int lane = threadIdx.x & 63, wave = threadIdx.x >> 6;
  const int q = lane >> 4, r = lane & 15;
  const long wbase = (long)blockIdx.x * 256 + wave * 64;
  bf16x8 bfr[2][3];
#pragma unroll
  for (int t = 0; t < 2; t++)
#pragma unroll
    for (int h = 0; h < 3; h++)
      bfr[t][h] = *reinterpret_cast<const bf16x8*>(wpack + ((t * 3 + h) * 64 + lane) * 8);
  float bv[2];
#pragma unroll
  for (int t = 0; t < 2; t++) bv[t] = sbias[t * 16 + r];
#pragma unroll
  for (int r4 = 0; r4 < 4; r4++) {
    const long row0 = wbase + r4 * 16;
    long m = row0 + r;
    long mm = m < N ? m : (long)N - 1;
    bf16x8 a0 = ldb8(hin + mm * 96 + q * 8);
    bf16x8 a1 = ldb8(hin + mm * 96 + 32 + q * 8);
    bf16x8 a2 = ldb8(hin + mm * 96 + 64 + q * 8);
    floatx4 acc[2];
#pragma unroll
    for (int t = 0; t < 2; t++) {
      acc[t] = (floatx4){bv[t], bv[t], bv[t], bv[t]};
      acc[t] = mfma16(a0, bfr[t][0], acc[t]);
      acc[t] = mfma16(a1, bfr[t][1], acc[t]);
      acc[t] = mfma16(a2, bfr[t][2], acc[t]);
    }
#pragma unroll
    for (int t = 0; t < 2; t++)
#pragma unroll
      for (int gi = 0; gi < 4; gi++) {
        long row = row0 + q * 4 + gi;
        if (row < N) {
          float v = acc[t][gi];
          if (mode) ((u16*)outv)[row * 32 + t * 16 + r] = f2bf(v);
          else      ((float*)outv)[row * 32 + t * 16 + r] = v;
        }
      }
  }
}

// ---------------------------------------------------------------------------
extern "C" void kernel_launch(void* const* d_in, const int* in_sizes, int n_in,
                              void* d_out, int out_size, void* d_ws,
                              size_t ws_size, hipStream_t stream) {
  const int N = in_sizes[0] / 32;
  const int E = in_sizes[2] / 32;

  const void* x    = d_in[0];
  const int*  eidx = (const int*)d_in[1];  // [2][E]: row=eidx, col=eidx+E
  const void* ea   = d_in[2];
  const void *m1_g1 = d_in[5],  *m1_b1 = d_in[6];
  const void *m1_w1 = d_in[7],  *m1_c1 = d_in[8];
  const void *m1_g2 = d_in[9],  *m1_b2 = d_in[10];
  const void *m1_w2 = d_in[11], *m1_c2 = d_in[12];
  const void *m1_g3 = d_in[13], *m1_b3 = d_in[14];
  const void *m1_w3 = d_in[15], *m1_c3 = d_in[16];
  const void *m2_g1 = d_in[17], *m2_b1 = d_in[18];
  const void *m2_w1 = d_in[19], *m2_c1 = d_in[20];
  const void *m2_g2 = d_in[21], *m2_b2 = d_in[22];
  const void *m2_w2 = d_in[23], *m2_c2 = d_in[24];
  const void *m2_g3 = d_in[25], *m2_b3 = d_in[26];
  const void *m2_w3 = d_in[27], *m2_c3 = d_in[28];

  // workspace carve (16B-aligned chunks)
  char* w = (char*)d_ws;
  int*   modep  = (int*)w;   w += 16;
  u16*   h_s    = (u16*)w;   w += (size_t)E * 64 * 2;       // 102.4 MB (sorted)
  u16*   h2b    = (u16*)w;   w += (size_t)N * 96 * 2;       //  19.2 MB
  u16*   agg_b  = (u16*)w;   w += (size_t)N * 64 * 2;       //  12.8 MB
  u16*   xb     = (u16*)w;   w += (size_t)N * 32 * 2;       //   6.4 MB
  int*   offs   = (int*)w;   w += ((size_t)N + 4) * 4;
  int*   cursor = (int*)w;   w += ((size_t)N + 4) * 4;
  int*   ipos   = (int*)w;   w += (size_t)E * 4;            //   3.2 MB
  int*   nodeof = (int*)w;   w += (size_t)E * 4;            //   3.2 MB
  int*   bsum   = (int*)w;   w += 1024 * 4;
  // zero zone: s_e + deg + odeg + all stats buffers (contiguous)
  float* s_e    = (float*)w; w += (size_t)N * 64 * 4;       //  25.6 MB
  int*   deg    = (int*)w;   w += (size_t)N * 4;
  int*   odeg   = (int*)w;   w += (size_t)N * 4;
  float* stats0 = (float*)w; w += NBIN * 128 * 4;
  float* stats1 = (float*)w; w += NBIN * 128 * 4;
  float* stats2 = (float*)w; w += NBIN * 128 * 4;
  float* statsB0= (float*)w; w += NBIN * 192 * 4;
  float* statsB1= (float*)w; w += NBIN * 192 * 4;
  float* statsB2= (float*)w; w += NBIN * 192 * 4;
  const size_t zero_bytes = (size_t)N * 64 * 4 + (size_t)N * 8 +
                            NBIN * (128 * 3 + 192 * 3) * 4;
  // bf16 copy of ea (required by gemm1; ws is large enough in practice)
  u16* eab = (u16*)w;

  const int* erow = eidx;
  const int* ecol = eidx + E;
  const float invE = 1.0f / (float)E, invN = 1.0f / (float)N;
  const int gA = (E + 255) / 256, gA2 = (E + 511) / 512, gB = (N + 255) / 256;
  const int nb = (N + 1023) / 1024;

  detect_kernel<<<1, 256, 0, stream>>>((const u16*)x, modep);
  hipMemsetAsync(s_e, 0, zero_bytes, stream);

  // --- counting sort of edges by destination + degree histograms ---
  count2_kernel<<<1024, 256, 0, stream>>>(erow, ecol, E, odeg, deg);
  scan1_kernel<<<nb, 1024, 0, stream>>>(deg, N, offs, bsum);
  scan2_kernel<<<1, 1024, 0, stream>>>(bsum, nb, offs, N, E);
  scan3_kernel<<<nb, 1024, 0, stream>>>(offs, bsum, N, cursor);
  scatter_kernel<<<1024, 256, 0, stream>>>(ecol, E, cursor, ipos, nodeof);

  // --- merged input stats + xb/eab conversion ---
  stats_in_kernel<<<512 + EA_BLOCKS, 256, 0, stream>>>(x, odeg, N, ea, E,
                                                       stats0, statsB0, xb, eab,
                                                       modep);

  // --- phase A: edge MLP (h written destination-sorted; folds inlined) ---
  gemm1_kernel<<<gA2, 256, 0, stream>>>(
      xb, eab, erow, ipos, stats0, invE, m1_g1, m1_b1, m1_w1, m1_c1,
      h_s, E, stats1, modep);
  gemm2_kernel<<<gA, 256, 0, stream>>>(
      h_s, stats1, invE, m1_g2, m1_b2, m1_w2, m1_c2,
      E, stats2, offs, nodeof, s_e, modep);

  // --- aggregation GEMM ---
  gemmAgg_kernel<<<gB, 256, 0, stream>>>(
      s_e, deg, stats2, invE, m1_g3, m1_b3, m1_w3, m1_c3,
      agg_b, N, statsB0, modep);

  // --- phase B: node MLP ---
  gemmB1_kernel<<<gB, 256, 0, stream>>>(
      xb, agg_b, statsB0, invN, m2_g1, m2_b1, m2_w1, m2_c1,
      h2b, N, statsB1, modep);
  gemmB2_kernel<<<gB, 256, 0, stream>>>(
      h2b, statsB1, invN, m2_g2, m2_b2, m2_w2, m2_c2,
      h2b, N, statsB2, modep);
  gemmB3_kernel<<<gB, 256, 0, stream>>>(
      h2b, statsB2, invN, m2_g3, m2_b3, m2_w3, m2_c3,
      d_out, N, modep);
}

// Round 9
// 577.205 us; speedup vs baseline: 1.0790x; 1.0604x over previous
//
#include <hip/hip_runtime.h>

// ---------------------------------------------------------------------------
// NodeModel (GraphNet node block), MI355X / gfx950.
// v13: h_s ROUND-TRIP ELIMINATED (204MB). gemm1 -> stats-only (no h write);
//   gemm2r recomputes layer-1 h per dest-sorted position (gather via inverse
//   permutation ssrc/esort from scatter2), h lives only in LDS (swizzled hs),
//   layer-2 A-fragments read directly from hs, segsum unchanged.
//   Recomputed h is bit-identical (same MFMA, same inputs) -> numerics same.
// v12: gemm2 LDS packed, loads hoisted. v10: NBIN=64 atomic fix (+146us).
// MFMA layouts (verified): A[m=lane&15][k=(lane>>4)*8+j],
//   B[k=(lane>>4)*8+j][n=lane&15], C/D: col=lane&15, row=(lane>>4)*4+reg.
// hs swizzle: elem (row,col) at hs[row*64 + ((col>>4 ^ (row>>2)&3)<<4) + (col&15)].
// ---------------------------------------------------------------------------

typedef unsigned short u16;
typedef __bf16  bf16x8  __attribute__((ext_vector_type(8)));
typedef float   floatx4 __attribute__((ext_vector_type(4)));

#define NBIN 64
#define EA_BLOCKS 1024

__device__ __forceinline__ float bf2f(u16 u) {
  union { float f; unsigned int i; } v; v.i = ((unsigned int)u) << 16; return v.f;
}
__device__ __forceinline__ u16 f2bf(float f) {
  union { float f; unsigned int i; } v; v.f = f;
  unsigned int x = v.i;
  return (u16)((x + 0x7fffu + ((x >> 16) & 1u)) >> 16);  // RNE
}
__device__ __forceinline__ bf16x8 ldb8(const u16* p) {
  return *reinterpret_cast<const bf16x8*>(p);
}
__device__ __forceinline__ floatx4 mfma16(bf16x8 a, bf16x8 b, floatx4 c) {
  return __builtin_amdgcn_mfma_f32_16x16x32_bf16(a, b, c, 0, 0, 0);
}
// mode: 0 = float32, 1 = bf16
__device__ __forceinline__ float loadf(const void* p, long idx, int mode) {
  return mode ? bf2f(((const u16*)p)[idx]) : ((const float*)p)[idx];
}
__device__ __forceinline__ bf16x8 load8(const void* p, long idx, int mode) {
  if (mode) return ldb8((const u16*)p + idx);
  const float* f = (const float*)p + idx;
  bf16x8 r;
#pragma unroll
  for (int j = 0; j < 8; j++) r[j] = (__bf16)f[j];
  return r;
}

// ---------------- per-block BN fold: stats -> scale/offset -> packed W+bias
__device__ __forceinline__ void fold_block(
    const float* __restrict__ stats, float inv_rows,
    const void* __restrict__ g, const void* __restrict__ b,
    const void* __restrict__ W, const void* __restrict__ c,
    int K, int OUT, int mode,
    u16* wlds, u16* wpack, float* s_s, float* s_off, float* sbias) {
  const int tid = threadIdx.x;
  const int tot8 = (K * OUT) >> 3;  // always divisible by 8
  for (int i = tid; i < tot8; i += 256) {
    bf16x8 o;
    if (mode) {
      o = ldb8((const u16*)W + (size_t)i * 8);
    } else {
      const float* f = (const float*)W + (size_t)i * 8;
      float4 a = *(const float4*)f;
      float4 d = *(const float4*)(f + 4);
      o[0] = (__bf16)a.x; o[1] = (__bf16)a.y; o[2] = (__bf16)a.z; o[3] = (__bf16)a.w;
      o[4] = (__bf16)d.x; o[5] = (__bf16)d.y; o[6] = (__bf16)d.z; o[7] = (__bf16)d.w;
    }
    *reinterpret_cast<bf16x8*>(wlds + (size_t)i * 8) = o;
  }
  if (tid < K) {
    float sum = 0.f, sq = 0.f;
    for (int p = 0; p < NBIN; p++) {
      sum += stats[p * 2 * K + tid];
      sq  += stats[p * 2 * K + K + tid];
    }
    float m = sum * inv_rows, var = sq * inv_rows - m * m;
    float s = loadf(g, tid, mode) * rsqrtf(var + 1e-5f);
    s_s[tid] = s;
    s_off[tid] = loadf(b, tid, mode) - m * s;
  }
  __syncthreads();
  if (tid < OUT) {
    float acc = loadf(c, tid, mode);
    for (int k = 0; k < K; k++) acc += s_off[k] * bf2f(wlds[k * OUT + tid]);
    sbias[tid] = acc;
  }
  const int H = K >> 5, T = OUT >> 4;
  const int tot8p = T * H * 64;  // (T*H*512)/8
  for (int i8 = tid; i8 < tot8p; i8 += 256) {
    int lane = i8 & 63, th = i8 >> 6;
    int h = th % H, t = th / H;
    int kb = h * 32 + ((lane >> 4) << 3);
    int n = (t << 4) + (lane & 15);
    bf16x8 o;
#pragma unroll
    for (int j = 0; j < 8; j++)
      o[j] = (__bf16)(s_s[kb + j] * bf2f(wlds[(kb + j) * OUT + n]));
    *reinterpret_cast<bf16x8*>(wpack + (size_t)i8 * 8) = o;
  }
  __syncthreads();
}

// ---------------- dtype detection
__global__ void detect_kernel(const u16* __restrict__ x, int* __restrict__ modep) {
  __shared__ int cnt;
  if (threadIdx.x == 0) cnt = 0;
  __syncthreads();
  int weird = 0;
  for (int i = threadIdx.x; i < 1024; i += blockDim.x) {
    unsigned e = (x[i] >> 7) & 0xFFu;
    if (e == 0xFFu || e >= 0x90u || (e != 0u && e < 0x60u)) weird++;
  }
  atomicAdd(&cnt, weird);
  __syncthreads();
  if (threadIdx.x == 0) *modep = (cnt > 128) ? 0 : 1;
}

// ================= counting sort of edges by destination ====================
__global__ void count2_kernel(const int* __restrict__ row, const int* __restrict__ col,
                              int E, int* __restrict__ odeg, int* __restrict__ deg) {
  for (int e = blockIdx.x * blockDim.x + threadIdx.x; e < E;
       e += gridDim.x * blockDim.x) {
    atomicAdd(&odeg[row[e]], 1);
    atomicAdd(&deg[col[e]], 1);
  }
}

__global__ void scan1_kernel(const int* __restrict__ deg, int n,
                             int* __restrict__ excl, int* __restrict__ bsum) {
  __shared__ int tmp[2][1024];
  const int tid = threadIdx.x;
  const int i = blockIdx.x * 1024 + tid;
  int v = (i < n) ? deg[i] : 0;
  tmp[0][tid] = v;
  __syncthreads();
  int src = 0;
  for (int off = 1; off < 1024; off <<= 1) {
    int t = tmp[src][tid];
    if (tid >= off) t += tmp[src][tid - off];
    tmp[1 - src][tid] = t;
    src = 1 - src;
    __syncthreads();
  }
  if (i < n) excl[i] = tmp[src][tid] - v;
  if (tid == 1023) bsum[blockIdx.x] = tmp[src][1023];
}

// parallel exclusive scan of up to 1024 block sums
__global__ void scan2_kernel(int* __restrict__ bsum, int nb,
                             int* __restrict__ offsets, int N, int E) {
  __shared__ int tmp[2][1024];
  const int tid = threadIdx.x;
  int v = (tid < nb) ? bsum[tid] : 0;
  tmp[0][tid] = v;
  __syncthreads();
  int src = 0;
  for (int off = 1; off < 1024; off <<= 1) {
    int t = tmp[src][tid];
    if (tid >= off) t += tmp[src][tid - off];
    tmp[1 - src][tid] = t;
    src = 1 - src;
    __syncthreads();
  }
  if (tid < nb) bsum[tid] = tmp[src][tid] - v;
  if (tid == 0) offsets[N] = E;
}

__global__ void scan3_kernel(int* __restrict__ offsets, const int* __restrict__ bsum,
                             int n, int* __restrict__ cursor) {
  int i = blockIdx.x * 1024 + threadIdx.x;
  if (i < n) {
    int v = offsets[i] + bsum[blockIdx.x];
    offsets[i] = v;
    cursor[i] = v;
  }
}

// scatter: dest-sorted position pos gets edge e; record inverse permutation
// (esort[pos]=e, ssrc[pos]=row[e]) for gemm2r's recompute gather.
__global__ void scatter2_kernel(const int* __restrict__ row, const int* __restrict__ col,
                                int E, int* __restrict__ cursor,
                                int* __restrict__ nodeof,
                                int* __restrict__ esort, int* __restrict__ ssrc) {
  for (int e = blockIdx.x * blockDim.x + threadIdx.x; e < E;
       e += gridDim.x * blockDim.x) {
    int d = col[e];
    int pos = atomicAdd(&cursor[d], 1);
    nodeof[pos] = d;
    esort[pos] = e;
    ssrc[pos] = row[e];
  }
}

// ---------------- merged input stats (unchanged from v10)
__global__ void stats_in_kernel(const void* __restrict__ x,
                                const int* __restrict__ odeg, int N,
                                const void* __restrict__ ea, int E,
                                float* __restrict__ stats0,
                                float* __restrict__ statsB0,
                                u16* __restrict__ xb, u16* __restrict__ eab,
                                const int* __restrict__ modep) {
  const int mode = *modep;
  if (blockIdx.x < 512) {
    const int c = threadIdx.x & 31, rs = threadIdx.x >> 5;  // 8 rows/iter
    float s = 0.f, q = 0.f, ws = 0.f, wq = 0.f;
    for (long rr = (long)blockIdx.x * 8 + rs; rr < N; rr += 512 * 8) {
      float v = loadf(x, rr * 32 + c, mode);
      float w = (float)odeg[rr];
      xb[rr * 32 + c] = f2bf(v);
      s += v; q += v * v; ws += w * v; wq += w * v * v;
    }
    __shared__ float sm[4][256];
    sm[0][threadIdx.x] = s;  sm[1][threadIdx.x] = q;
    sm[2][threadIdx.x] = ws; sm[3][threadIdx.x] = wq;
    __syncthreads();
    if (threadIdx.x < 32) {
      for (int i = 1; i < 8; i++) {
        s  += sm[0][i * 32 + c]; q  += sm[1][i * 32 + c];
        ws += sm[2][i * 32 + c]; wq += sm[3][i * 32 + c];
      }
      const int bin = blockIdx.x & (NBIN - 1);
      atomicAdd(statsB0 + bin * 192 + c, s);
      atomicAdd(statsB0 + bin * 192 + 96 + c, q);
      atomicAdd(stats0 + bin * 128 + c, ws);
      atomicAdd(stats0 + bin * 128 + 64 + c, wq);
    }
  } else {
    const int bid = blockIdx.x - 512;                        // 0..EA_BLOCKS-1
    const int cg = threadIdx.x & 3, rsub = threadIdx.x >> 2;  // 64 rows/iter
    const int lane = threadIdx.x & 63, wave = threadIdx.x >> 6;
    float s[8], q[8];
#pragma unroll
    for (int j = 0; j < 8; j++) { s[j] = 0.f; q[j] = 0.f; }
    for (long rr = (long)bid * 64 + rsub; rr < E; rr += (long)EA_BLOCKS * 64) {
      float f0[8];
      if (mode) {
        bf16x8 v = ldb8((const u16*)ea + rr * 32 + cg * 8);
#pragma unroll
        for (int j = 0; j < 8; j++) f0[j] = (float)v[j];
      } else {
        const float* p = (const float*)ea + rr * 32 + cg * 8;
        float4 a = *(const float4*)p;
        float4 b = *(const float4*)(p + 4);
        f0[0]=a.x; f0[1]=a.y; f0[2]=a.z; f0[3]=a.w;
        f0[4]=b.x; f0[5]=b.y; f0[6]=b.z; f0[7]=b.w;
      }
      if (eab) {
        bf16x8 o;
#pragma unroll
        for (int j = 0; j < 8; j++) o[j] = (__bf16)f0[j];
        *reinterpret_cast<bf16x8*>(eab + rr * 32 + cg * 8) = o;
      }
#pragma unroll
      for (int j = 0; j < 8; j++) { s[j] += f0[j]; q[j] += f0[j] * f0[j]; }
    }
#pragma unroll
    for (int st = 4; st < 64; st <<= 1) {
#pragma unroll
      for (int j = 0; j < 8; j++) {
        s[j] += __shfl_xor(s[j], st, 64);
        q[j] += __shfl_xor(q[j], st, 64);
      }
    }
    __shared__ float red[4][64];
    if (lane < 4) {
#pragma unroll
      for (int j = 0; j < 8; j++) {
        red[wave][lane * 8 + j] = s[j];
        red[wave][32 + lane * 8 + j] = q[j];
      }
    }
    __syncthreads();
    if (wave == 0 && lane < 4) {
      float* o = stats0 + (blockIdx.x & (NBIN - 1)) * 128;
#pragma unroll
      for (int j = 0; j < 8; j++) {
        float ss = red[0][lane * 8 + j] + red[1][lane * 8 + j] +
                   red[2][lane * 8 + j] + red[3][lane * 8 + j];
        float qq = red[0][32 + lane * 8 + j] + red[1][32 + lane * 8 + j] +
                   red[2][32 + lane * 8 + j] + red[3][32 + lane * 8 + j];
        atomicAdd(o + 32 + lane * 8 + j, ss);
        atomicAdd(o + 96 + lane * 8 + j, qq);
      }
    }
  }
}

// ======== GEMM 1 (stats only): layer-1 output stats; h NOT stored ==========
__global__ __launch_bounds__(256) void gemm1_kernel(
    const u16* __restrict__ xb, const u16* __restrict__ eab,
    const int* __restrict__ erow,
    const float* __restrict__ stats0, float invE,
    const void* __restrict__ g, const void* __restrict__ b,
    const void* __restrict__ W, const void* __restrict__ c,
    int E, float* __restrict__ statsOut, const int* __restrict__ modep) {
  __shared__ u16 wlds[4096], wpack[4096];
  __shared__ float s_s[64], s_off[64], sbias[64];
  __shared__ float sm[512];
  const int mode = *modep;
  fold_block(stats0, invE, g, b, W, c, 64, 64, mode, wlds, wpack, s_s, s_off, sbias);
  const int lane = threadIdx.x & 63, wave = threadIdx.x >> 6;
  const int q = lane >> 4, r = lane & 15;
  const long wbase = (long)blockIdx.x * 256 + wave * 64;
  bf16x8 bfr[4][2];
#pragma unroll
  for (int t = 0; t < 4; t++)
#pragma unroll
    for (int h = 0; h < 2; h++)
      bfr[t][h] = *reinterpret_cast<const bf16x8*>(wpack + ((t * 2 + h) * 64 + lane) * 8);
  float bv[4];
#pragma unroll
  for (int t = 0; t < 4; t++) bv[t] = sbias[t * 16 + r];
  // hoisted gather (8x16B in flight)
  bf16x8 a0v[4], a1v[4];
#pragma unroll
  for (int r4 = 0; r4 < 4; r4++) {
    long e = wbase + r4 * 16 + r; if (e > E - 1) e = E - 1;
    int src = erow[e];
    a0v[r4] = ldb8(xb + (long)src * 32 + q * 8);
    a1v[r4] = ldb8(eab + e * 32 + q * 8);
  }
  float s_[4] = {0, 0, 0, 0}, q_[4] = {0, 0, 0, 0};
#pragma unroll
  for (int r4 = 0; r4 < 4; r4++) {
    floatx4 acc[4];
#pragma unroll
    for (int t = 0; t < 4; t++) {
      acc[t] = (floatx4){bv[t], bv[t], bv[t], bv[t]};
      acc[t] = mfma16(a0v[r4], bfr[t][0], acc[t]);
      acc[t] = mfma16(a1v[r4], bfr[t][1], acc[t]);
    }
#pragma unroll
    for (int gi = 0; gi < 4; gi++) {
      long row = wbase + r4 * 16 + q * 4 + gi;
      if (row < E) {
#pragma unroll
        for (int t = 0; t < 4; t++) {
          float v = acc[t][gi];
          v = v > 0.f ? v : 0.1f * v;
          float vv = bf2f(f2bf(v));  // same rounding as stored-h path
          s_[t] += vv; q_[t] += vv * vv;
        }
      }
    }
  }
#pragma unroll
  for (int t = 0; t < 4; t++) {
    float s = s_[t], qq = q_[t];
    s  += __shfl_xor(s, 16, 64);  s  += __shfl_xor(s, 32, 64);
    qq += __shfl_xor(qq, 16, 64); qq += __shfl_xor(qq, 32, 64);
    if (lane < 16) { sm[wave * 128 + t * 16 + lane] = s; sm[wave * 128 + 64 + t * 16 + lane] = qq; }
  }
  __syncthreads();
  if (threadIdx.x < 128) {
    int which = threadIdx.x >> 6, cc = threadIdx.x & 63;
    float v = 0.f;
    for (int w = 0; w < 4; w++) v += sm[w * 128 + which * 64 + cc];
    atomicAdd(statsOut + (blockIdx.x & (NBIN - 1)) * 128 + which * 64 + cc, v);
  }
}

// ======== GEMM 2r (fused recompute): gather -> layer1 -> LDS -> layer2 ->
//          segsum -> s_e. h never touches global memory. =====================
__global__ __launch_bounds__(256) void gemm2r_kernel(
    const u16* __restrict__ xb, const u16* __restrict__ eab,
    const int* __restrict__ ssrc, const int* __restrict__ esort,
    const float* __restrict__ stats0, const float* __restrict__ stats1,
    float invE,
    const void* __restrict__ g1, const void* __restrict__ b1,
    const void* __restrict__ W1, const void* __restrict__ c1,
    const void* __restrict__ g2, const void* __restrict__ b2,
    const void* __restrict__ W2, const void* __restrict__ c2,
    int E, float* __restrict__ statsOut,
    const int* __restrict__ offs, const int* __restrict__ nodeof,
    float* __restrict__ s_e, const int* __restrict__ modep) {
  __shared__ union {
    struct { u16 wlds[4096]; float s_s[64]; float s_off[64]; } f;
    u16 hs[256 * 64];
  } uA;                                               // 32 KB
  __shared__ union { u16 wpack1[4096]; float sm[512]; } uB;  // 8 KB
  __shared__ u16 wpack2[4096];                        // 8 KB (persists)
  __shared__ float sbias1[64], sbias2[64];
  const int mode = *modep;
  fold_block(stats0, invE, g1, b1, W1, c1, 64, 64, mode,
             uA.f.wlds, uB.wpack1, uA.f.s_s, uA.f.s_off, sbias1);
  fold_block(stats1, invE, g2, b2, W2, c2, 64, 64, mode,
             uA.f.wlds, wpack2, uA.f.s_s, uA.f.s_off, sbias2);
  const int lane = threadIdx.x & 63, wave = threadIdx.x >> 6;
  const int q = lane >> 4, r = lane & 15;
  const long bbase = (long)blockIdx.x * 256;
  const long wbase = bbase + wave * 64;
  bf16x8 bfr1[4][2];
#pragma unroll
  for (int t = 0; t < 4; t++)
#pragma unroll
    for (int h = 0; h < 2; h++)
      bfr1[t][h] = *reinterpret_cast<const bf16x8*>(uB.wpack1 + ((t * 2 + h) * 64 + lane) * 8);
  float bv1[4];
#pragma unroll
  for (int t = 0; t < 4; t++) bv1[t] = sbias1[t * 16 + r];
  // gather via inverse permutation (sorted position -> edge/source)
  bf16x8 A0[4], A1[4];
#pragma unroll
  for (int r4 = 0; r4 < 4; r4++) {
    long i = wbase + r4 * 16 + r; if (i > E - 1) i = E - 1;
    int s = ssrc[i];
    long ee = esort[i];
    A0[r4] = ldb8(xb + (long)s * 32 + q * 8);
    A1[r4] = ldb8(eab + ee * 32 + q * 8);
  }
  // phase 1: recompute layer-1 h -> swizzled hs (wave-private rows)
#pragma unroll
  for (int r4 = 0; r4 < 4; r4++) {
    floatx4 acc[4];
#pragma unroll
    for (int t = 0; t < 4; t++) {
      acc[t] = (floatx4){bv1[t], bv1[t], bv1[t], bv1[t]};
      acc[t] = mfma16(A0[r4], bfr1[t][0], acc[t]);
      acc[t] = mfma16(A1[r4], bfr1[t][1], acc[t]);
    }
    const int lbase = wave * 64 + r4 * 16;
#pragma unroll
    for (int t = 0; t < 4; t++) {
      const int colx = ((t ^ q) << 4) + r;
#pragma unroll
      for (int gi = 0; gi < 4; gi++) {
        float v = acc[t][gi];
        v = v > 0.f ? v : 0.1f * v;
        uA.hs[(lbase + q * 4 + gi) * 64 + colx] = f2bf(v);
      }
    }
  }
  // layer-2 weights (wpack2/sbias2 persist in dedicated LDS)
  bf16x8 bfr2[4][2];
#pragma unroll
  for (int t = 0; t < 4; t++)
#pragma unroll
    for (int h = 0; h < 2; h++)
      bfr2[t][h] = *reinterpret_cast<const bf16x8*>(wpack2 + ((t * 2 + h) * 64 + lane) * 8);
  float bv2[4];
#pragma unroll
  for (int t = 0; t < 4; t++) bv2[t] = sbias2[t * 16 + r];
  // phase 2: layer-2 from hs; each r4-subtile's reads/writes are wave-private
  float s_[4] = {0, 0, 0, 0}, q_[4] = {0, 0, 0, 0};
  const int qw = (r >> 2) & 3;
#pragma unroll
  for (int r4 = 0; r4 < 4; r4++) {
    const int lbase = wave * 64 + r4 * 16;
    const int lrow = lbase + r;  // A-fragment row m = lane&15
    bf16x8 a0 = *reinterpret_cast<const bf16x8*>(
        &uA.hs[lrow * 64 + (((q >> 1) ^ qw) << 4) + (q & 1) * 8]);
    bf16x8 a1 = *reinterpret_cast<const bf16x8*>(
        &uA.hs[lrow * 64 + ((((q >> 1) + 2) ^ qw) << 4) + (q & 1) * 8]);
    floatx4 acc[4];
#pragma unroll
    for (int t = 0; t < 4; t++) {
      acc[t] = (floatx4){bv2[t], bv2[t], bv2[t], bv2[t]};
      acc[t] = mfma16(a0, bfr2[t][0], acc[t]);
      acc[t] = mfma16(a1, bfr2[t][1], acc[t]);
    }
#pragma unroll
    for (int t = 0; t < 4; t++) {
      const int colx = ((t ^ q) << 4) + r;
#pragma unroll
      for (int gi = 0; gi < 4; gi++) {
        long row = bbase + lbase + q * 4 + gi;
        float v = acc[t][gi];
        v = v > 0.f ? v : 0.1f * v;
        u16 st = f2bf(v);
        uA.hs[(lbase + q * 4 + gi) * 64 + colx] = st;
        if (row < E) {
          float vv = bf2f(st);
          s_[t] += vv; q_[t] += vv * vv;
        }
      }
    }
  }
  __syncthreads();  // layer-2 hs visible to all waves
  // ---- segment-sum over this block's 256 sorted rows ----
  const long blockEnd = (bbase + 256 < (long)E) ? bbase + 256 : (long)E;
  const int first = nodeof[bbase];
  const int last  = nodeof[blockEnd - 1];
  for (int idx = first + wave; idx <= last; idx += 4) {
    int st = offs[idx], en = offs[idx + 1];
    long cs = st < bbase ? bbase : (long)st;
    long ce = (long)en > blockEnd ? blockEnd : (long)en;
    if (cs >= ce) continue;
    float acc = 0.f;
    for (long i = cs - bbase; i < ce - bbase; i++)
      acc += bf2f(uA.hs[i * 64 + (lane ^ (int)(((i >> 2) & 3) << 4))]);
    if ((long)st >= bbase && (long)en <= blockEnd)
      s_e[(long)idx * 64 + lane] = acc;
    else
      atomicAdd(s_e + (long)idx * 64 + lane, acc);
  }
  __syncthreads();  // segsum done; wpack1 long dead -> sm safe
#pragma unroll
  for (int t = 0; t < 4; t++) {
    float s = s_[t], qq = q_[t];
    s  += __shfl_xor(s, 16, 64);  s  += __shfl_xor(s, 32, 64);
    qq += __shfl_xor(qq, 16, 64); qq += __shfl_xor(qq, 32, 64);
    if (lane < 16) { uB.sm[wave * 128 + t * 16 + lane] = s; uB.sm[wave * 128 + 64 + t * 16 + lane] = qq; }
  }
  __syncthreads();
  if (threadIdx.x < 128) {
    int which = threadIdx.x >> 6, cc = threadIdx.x & 63;
    float v = 0.f;
    for (int w = 0; w < 4; w++) v += uB.sm[w * 128 + which * 64 + cc];
    atomicAdd(statsOut + (blockIdx.x & (NBIN - 1)) * 128 + which * 64 + cc, v);
  }
}

// ======== GEMM Agg: agg_b[n] = bf16( bf16(s_e[n]) @ W3' + deg[n]*b3' ) ======
__global__ __launch_bounds__(256) void gemmAgg_kernel(
    const float* __restrict__ s_e, const int* __restrict__ deg,
    const float* __restrict__ stats2, float invE,
    const void* __restrict__ g, const void* __restrict__ b,
    const void* __restrict__ W, const void* __restrict__ c,
    u16* __restrict__ agg_b, int N, float* __restrict__ statsOut,
    const int* __restrict__ modep) {
  __shared__ u16 wlds[4096], wpack[4096];
  __shared__ float s_s[64], s_off[64], sbias[64];
  __shared__ float sm[512];
  const int mode = *modep;
  fold_block(stats2, invE, g, b, W, c, 64, 64, mode, wlds, wpack, s_s, s_off, sbias);
  const int lane = threadIdx.x & 63, wave = threadIdx.x >> 6;
  const int q = lane >> 4, r = lane & 15;
  const long wbase = (long)blockIdx.x * 256 + wave * 64;
  bf16x8 bfr[4][2];
#pragma unroll
  for (int t = 0; t < 4; t++)
#pragma unroll
    for (int h = 0; h < 2; h++)
      bfr[t][h] = *reinterpret_cast<const bf16x8*>(wpack + ((t * 2 + h) * 64 + lane) * 8);
  float bv[4];
#pragma unroll
  for (int t = 0; t < 4; t++) bv[t] = sbias[t * 16 + r];
  float s_[4] = {0, 0, 0, 0}, q_[4] = {0, 0, 0, 0};
#pragma unroll
  for (int r4 = 0; r4 < 4; r4++) {
    const long row0 = wbase + r4 * 16;
    long m = row0 + r;
    long mm = m < N ? m : (long)N - 1;
    bf16x8 a0, a1;
    {
      const float* ap = s_e + mm * 64 + q * 8;
#pragma unroll
      for (int j = 0; j < 8; j++) a0[j] = (__bf16)ap[j];
#pragma unroll
      for (int j = 0; j < 8; j++) a1[j] = (__bf16)ap[32 + j];
    }
    floatx4 acc[4];
#pragma unroll
    for (int t = 0; t < 4; t++) {
      acc[t] = (floatx4){0.f, 0.f, 0.f, 0.f};
      acc[t] = mfma16(a0, bfr[t][0], acc[t]);
      acc[t] = mfma16(a1, bfr[t][1], acc[t]);
    }
#pragma unroll
    for (int gi = 0; gi < 4; gi++) {
      long row = row0 + q * 4 + gi;
      if (row < N) {
        float d = (float)deg[row];
#pragma unroll
        for (int t = 0; t < 4; t++) {
          float v = acc[t][gi] + d * bv[t];
          agg_b[row * 64 + t * 16 + r] = f2bf(v);
          s_[t] += v; q_[t] += v * v;
        }
      }
    }
  }
#pragma unroll
  for (int t = 0; t < 4; t++) {
    float s = s_[t], qq = q_[t];
    s  += __shfl_xor(s, 16, 64);  s  += __shfl_xor(s, 32, 64);
    qq += __shfl_xor(qq, 16, 64); qq += __shfl_xor(qq, 32, 64);
    if (lane < 16) { sm[wave * 128 + t * 16 + lane] = s; sm[wave * 128 + 64 + t * 16 + lane] = qq; }
  }
  __syncthreads();
  if (threadIdx.x < 128) {
    int which = threadIdx.x >> 6, cc = threadIdx.x & 63;
    float v = 0.f;
    for (int w = 0; w < 4; w++) v += sm[w * 128 + which * 64 + cc];
    // statsB0 [NBIN][192]: sums [0..95], sumsq [96..191]; agg = cols 32..95
    atomicAdd(statsOut + (blockIdx.x & (NBIN - 1)) * 192 + which * 96 + 32 + cc, v);
  }
}

// ======== GEMM B1: [xb, agg_b] (K=96 -> 96), LReLU, stats =================
__global__ __launch_bounds__(256) void gemmB1_kernel(
    const u16* __restrict__ xb, const u16* __restrict__ agg_b,
    const float* __restrict__ statsB0, float invN,
    const void* __restrict__ g, const void* __restrict__ b,
    const void* __restrict__ W, const void* __restrict__ c,
    u16* __restrict__ hout, int N, float* __restrict__ statsOut,
    const int* __restrict__ modep) {
  __shared__ u16 wlds[9216], wpack[9216];
  __shared__ float s_s[96], s_off[96], sbias[96];
  __shared__ float sm[768];
  const int mode = *modep;
  fold_block(statsB0, invN, g, b, W, c, 96, 96, mode, wlds, wpack, s_s, s_off, sbias);
  const int lane = threadIdx.x & 63, wave = threadIdx.x >> 6;
  const int q = lane >> 4, r = lane & 15;
  const long wbase = (long)blockIdx.x * 256 + wave * 64;
  bf16x8 bfr[6][3];
#pragma unroll
  for (int t = 0; t < 6; t++)
#pragma unroll
    for (int h = 0; h < 3; h++)
      bfr[t][h] = *reinterpret_cast<const bf16x8*>(wpack + ((t * 3 + h) * 64 + lane) * 8);
  float bv[6];
#pragma unroll
  for (int t = 0; t < 6; t++) bv[t] = sbias[t * 16 + r];
  float s_[6] = {0, 0, 0, 0, 0, 0}, q_[6] = {0, 0, 0, 0, 0, 0};
#pragma unroll
  for (int r4 = 0; r4 < 4; r4++) {
    const long row0 = wbase + r4 * 16;
    long m = row0 + r;
    long mm = m < N ? m : (long)N - 1;
    bf16x8 a0 = ldb8(xb + mm * 32 + q * 8);
    bf16x8 a1 = ldb8(agg_b + mm * 64 + q * 8);
    bf16x8 a2 = ldb8(agg_b + mm * 64 + 32 + q * 8);
    floatx4 acc[6];
#pragma unroll
    for (int t = 0; t < 6; t++) {
      acc[t] = (floatx4){bv[t], bv[t], bv[t], bv[t]};
      acc[t] = mfma16(a0, bfr[t][0], acc[t]);
      acc[t] = mfma16(a1, bfr[t][1], acc[t]);
      acc[t] = mfma16(a2, bfr[t][2], acc[t]);
    }
#pragma unroll
    for (int t = 0; t < 6; t++)
#pragma unroll
      for (int gi = 0; gi < 4; gi++) {
        long row = row0 + q * 4 + gi;
        if (row < N) {
          float v = acc[t][gi];
          v = v > 0.f ? v : 0.1f * v;
          u16 st = f2bf(v);
          hout[row * 96 + t * 16 + r] = st;
          float vv = bf2f(st);
          s_[t] += vv; q_[t] += vv * vv;
        }
      }
  }
#pragma unroll
  for (int t = 0; t < 6; t++) {
    float s = s_[t], qq = q_[t];
    s  += __shfl_xor(s, 16, 64);  s  += __shfl_xor(s, 32, 64);
    qq += __shfl_xor(qq, 16, 64); qq += __shfl_xor(qq, 32, 64);
    if (lane < 16) { sm[wave * 192 + t * 16 + lane] = s; sm[wave * 192 + 96 + t * 16 + lane] = qq; }
  }
  __syncthreads();
  if (threadIdx.x < 192) {
    int which = threadIdx.x / 96, cc = threadIdx.x % 96;
    float v = 0.f;
    for (int w = 0; w < 4; w++) v += sm[w * 192 + which * 96 + cc];
    atomicAdd(statsOut + (blockIdx.x & (NBIN - 1)) * 192 + which * 96 + cc, v);
  }
}

// ======== GEMM B2: h[N,96] -> h[N,96] in place, LReLU, stats ===============
__global__ __launch_bounds__(256) void gemmB2_kernel(
    const u16* __restrict__ hin,
    const float* __restrict__ statsB1, float invN,
    const void* __restrict__ g, const void* __restrict__ b,
    const void* __restrict__ W, const void* __restrict__ c,
    u16* __restrict__ hout, int N, float* __restrict__ statsOut,
    const int* __restrict__ modep) {
  __shared__ u16 wlds[9216], wpack[9216];
  __shared__ float s_s[96], s_off[96], sbias[96];
  __shared__ float sm[768];
  const int mode = *modep;
  fold_block(statsB1, invN, g, b, W, c, 96, 96, mode, wlds, wpack, s_s, s_off, sbias);
  const int lane = threadIdx.x & 63, wave = threadIdx.x >> 6;
  const int q = lane >> 4, r = lane & 15;
  const long wbase = (long)blockIdx.x * 256 + wave * 64;
  bf16x8 bfr[6][3];
#pragma unroll
  for (int t = 0; t < 6; t++)
#pragma unroll
    for (int h = 0; h < 3; h++)
      bfr[t][h] = *reinterpret_cast<const bf16x8*>(wpack + ((t * 3 + h) * 64 + lane) * 8);
  float bv[6];
#pragma unroll
  for (int t = 0; t < 6; t++) bv[t] = sbias[t * 16 + r];
  float s_[6] = {0, 0, 0, 0, 0, 0}, q_[6] = {0, 0, 0, 0, 0, 0};
#pragma unroll
  for (int r4 = 0; r4 < 4; r4++) {
    const long row0 = wbase + r4 * 16;
    long m = row0 + r;
    long mm = m < N ? m : (long)N - 1;
    bf16x8 a0 = ldb8(hin + mm * 96 + q * 8);
    bf16x8 a1 = ldb8(hin + mm * 96 + 32 + q * 8);
    bf16x8 a2 = ldb8(hin + mm * 96 + 64 + q * 8);
    floatx4 acc[6];
#pragma unroll
    for (int t = 0; t < 6; t++) {
      acc[t] = (floatx4){bv[t], bv[t], bv[t], bv[t]};
      acc[t] = mfma16(a0, bfr[t][0], acc[t]);
      acc[t] = mfma16(a1, bfr[t][1], acc[t]);
      acc[t] = mfma16(a2, bfr[t][2], acc[t]);
    }
#pragma unroll
    for (int t = 0; t < 6; t++)
#pragma unroll
      for (int gi = 0; gi < 4; gi++) {
        long row = row0 + q * 4 + gi;
        if (row < N) {
          float v = acc[t][gi];
          v = v > 0.f ? v : 0.1f * v;
          u16 st = f2bf(v);
          hout[row * 96 + t * 16 + r] = st;
          float vv = bf2f(st);
          s_[t] += vv; q_[t] += vv * vv;
        }
      }
  }
#pragma unroll
  for (int t = 0; t < 6; t++) {
    float s = s_[t], qq = q_[t];
    s  += __shfl_xor(s, 16, 64);  s  += __shfl_xor(s, 32, 64);
    qq += __shfl_xor(qq, 16, 64); qq += __shfl_xor(qq, 32, 64);
    if (lane < 16) { sm[wave * 192 + t * 16 + lane] = s; sm[wave * 192 + 96 + t * 16 + lane] = qq; }
  }
  __syncthreads();
  if (threadIdx.x < 192) {
    int which = threadIdx.x / 96, cc = threadIdx.x % 96;
    float v = 0.f;
    for (int w = 0; w < 4; w++) v += sm[w * 192 + which * 96 + cc];
    atomicAdd(statsOut + (blockIdx.x & (NBIN - 1)) * 192 + which * 96 + cc, v);
  }
}

// ======== GEMM B3: h[N,96] -> out[N,32], no activation =====================
__global__ __launch_bounds__(256) void gemmB3_kernel(
    const u16* __restrict__ hin,
    const float* __restrict__ statsB2, float invN,
    const void* __restrict__ g, const void* __restrict__ b,
    const void* __restrict__ W, const void* __restrict__ c,
    void* __restrict__ outv, int N, const int* __restrict__ modep) {
  __shared__ u16 wlds[3072], wpack[3072];
  __shared__ float s_s[96], s_off[96], sbias[32];
  const int mode = *modep;
  fold_block(statsB2, invN, g, b, W, c, 96, 32, mode, wlds, wpack, s_s, s_off, sbias);
  const int lane = threadIdx.x & 63, wave = threadIdx.x >> 6;
  const int q = lane >> 4, r = lane & 15;
  const long wbase = (long)blockIdx.x * 256 + wave * 64;
  bf16x8 bfr[2][3];
#pragma unroll
  for (int t = 0; t < 2; t++)
#pragma unroll
    for (int h = 0; h < 3; h++)
      bfr[t][h] = *reinterpret_cast<const bf16x8*>(wpack + ((t * 3 + h) * 64 + lane) * 8);
  float bv[2];
#pragma unroll
  for (int t = 0; t < 2; t++) bv[t] = sbias[t * 16 + r];
#pragma unroll
  for (int r4 = 0; r4 < 4; r4++) {
    const long row0 = wbase + r4 * 16;
    long m = row0 + r;
    long mm = m < N ? m : (long)N - 1;
    bf16x8 a0 = ldb8(hin + mm * 96 + q * 8);
    bf16x8 a1 = ldb8(hin + mm * 96 + 32 + q * 8);
    bf16x8 a2 = ldb8(hin + mm * 96 + 64 + q * 8);
    floatx4 acc[2];
#pragma unroll
    for (int t = 0; t < 2; t++) {
      acc[t] = (floatx4){bv[t], bv[t], bv[t], bv[t]};
      acc[t] = mfma16(a0, bfr[t][0], acc[t]);
      acc[t] = mfma16(a1, bfr[t][1], acc[t]);
      acc[t] = mfma16(a2, bfr[t][2], acc[t]);
    }
#pragma unroll
    for (int t = 0; t < 2; t++)
#pragma unroll
      for (int gi = 0; gi < 4; gi++) {
        long row = row0 + q * 4 + gi;
        if (row < N) {
          float v = acc[t][gi];
          if (mode) ((u16*)outv)[row * 32 + t * 16 + r] = f2bf(v);
          else      ((float*)outv)[row * 32 + t * 16 + r] = v;
        }
      }
  }
}

// ---------------------------------------------------------------------------
extern "C" void kernel_launch(void* const* d_in, const int* in_sizes, int n_in,
                              void* d_out, int out_size, void* d_ws,
                              size_t ws_size, hipStream_t stream) {
  const int N = in_sizes[0] / 32;
  const int E = in_sizes[2] / 32;

  const void* x    = d_in[0];
  const int*  eidx = (const int*)d_in[1];  // [2][E]: row=eidx, col=eidx+E
  const void* ea   = d_in[2];
  const void *m1_g1 = d_in[5],  *m1_b1 = d_in[6];
  const void *m1_w1 = d_in[7],  *m1_c1 = d_in[8];
  const void *m1_g2 = d_in[9],  *m1_b2 = d_in[10];
  const void *m1_w2 = d_in[11], *m1_c2 = d_in[12];
  const void *m1_g3 = d_in[13], *m1_b3 = d_in[14];
  const void *m1_w3 = d_in[15], *m1_c3 = d_in[16];
  const void *m2_g1 = d_in[17], *m2_b1 = d_in[18];
  const void *m2_w1 = d_in[19], *m2_c1 = d_in[20];
  const void *m2_g2 = d_in[21], *m2_b2 = d_in[22];
  const void *m2_w2 = d_in[23], *m2_c2 = d_in[24];
  const void *m2_g3 = d_in[25], *m2_b3 = d_in[26];
  const void *m2_w3 = d_in[27], *m2_c3 = d_in[28];

  // workspace carve (16B-aligned chunks); h_s eliminated (v13)
  char* w = (char*)d_ws;
  int*   modep  = (int*)w;   w += 16;
  u16*   h2b    = (u16*)w;   w += (size_t)N * 96 * 2;       //  19.2 MB
  u16*   agg_b  = (u16*)w;   w += (size_t)N * 64 * 2;       //  12.8 MB
  u16*   xb     = (u16*)w;   w += (size_t)N * 32 * 2;       //   6.4 MB
  int*   offs   = (int*)w;   w += ((size_t)N + 4) * 4;
  int*   cursor = (int*)w;   w += ((size_t)N + 4) * 4;
  int*   esort  = (int*)w;   w += (size_t)E * 4;            //   3.2 MB
  int*   ssrc   = (int*)w;   w += (size_t)E * 4;            //   3.2 MB
  int*   nodeof = (int*)w;   w += (size_t)E * 4;            //   3.2 MB
  int*   bsum   = (int*)w;   w += 1024 * 4;
  // zero zone: s_e + deg + odeg + all stats buffers (contiguous)
  float* s_e    = (float*)w; w += (size_t)N * 64 * 4;       //  25.6 MB
  int*   deg    = (int*)w;   w += (size_t)N * 4;
  int*   odeg   = (int*)w;   w += (size_t)N * 4;
  float* stats0 = (float*)w; w += NBIN * 128 * 4;
  float* stats1 = (float*)w; w += NBIN * 128 * 4;
  float* stats2 = (float*)w; w += NBIN * 128 * 4;
  float* statsB0= (float*)w; w += NBIN * 192 * 4;
  float* statsB1= (float*)w; w += NBIN * 192 * 4;
  float* statsB2= (float*)w; w += NBIN * 192 * 4;
  const size_t zero_bytes = (size_t)N * 64 * 4 + (size_t)N * 8 +
                            NBIN * (128 * 3 + 192 * 3) * 4;
  // bf16 copy of ea
  u16* eab = (u16*)w;

  const int* erow = eidx;
  const int* ecol = eidx + E;
  const float invE = 1.0f / (float)E, invN = 1.0f / (float)N;
  const int gA = (E + 255) / 256, gB = (N + 255) / 256;
  const int nb = (N + 1023) / 1024;

  detect_kernel<<<1, 256, 0, stream>>>((const u16*)x, modep);
  hipMemsetAsync(s_e, 0, zero_bytes, stream);

  // --- counting sort of edges by destination + degree histograms ---
  count2_kernel<<<1024, 256, 0, stream>>>(erow, ecol, E, odeg, deg);
  scan1_kernel<<<nb, 1024, 0, stream>>>(deg, N, offs, bsum);
  scan2_kernel<<<1, 1024, 0, stream>>>(bsum, nb, offs, N, E);
  scan3_kernel<<<nb, 1024, 0, stream>>>(offs, bsum, N, cursor);
  scatter2_kernel<<<1024, 256, 0, stream>>>(erow, ecol, E, cursor,
                                            nodeof, esort, ssrc);

  // --- merged input stats + xb/eab conversion ---
  stats_in_kernel<<<512 + EA_BLOCKS, 256, 0, stream>>>(x, odeg, N, ea, E,
                                                       stats0, statsB0, xb, eab,
                                                       modep);

  // --- phase A: layer-1 stats (no h store), then fused recompute+layer2 ---
  gemm1_kernel<<<gA, 256, 0, stream>>>(
      xb, eab, erow, stats0, invE, m1_g1, m1_b1, m1_w1, m1_c1,
      E, stats1, modep);
  gemm2r_kernel<<<gA, 256, 0, stream>>>(
      xb, eab, ssrc, esort, stats0, stats1, invE,
      m1_g1, m1_b1, m1_w1, m1_c1,
      m1_g2, m1_b2, m1_w2, m1_c2,
      E, stats2, offs, nodeof, s_e, modep);

  // --- aggregation GEMM ---
  gemmAgg_kernel<<<gB, 256, 0, stream>>>(
      s_e, deg, stats2, invE, m1_g3, m1_b3, m1_w3, m1_c3,
      agg_b, N, statsB0, modep);

  // --- phase B: node MLP ---
  gemmB1_kernel<<<gB, 256, 0, stream>>>(
      xb, agg_b, statsB0, invN, m2_g1, m2_b1, m2_w1, m2_c1,
      h2b, N, statsB1, modep);
  gemmB2_kernel<<<gB, 256, 0, stream>>>(
      h2b, statsB1, invN, m2_g2, m2_b2, m2_w2, m2_c2,
      h2b, N, statsB2, modep);
  gemmB3_kernel<<<gB, 256, 0, stream>>>(
      h2b, statsB2, invN, m2_g3, m2_b3, m2_w3, m2_c3,
      d_out, N, modep);
}